// Round 1
// baseline (2286.540 us; speedup 1.0000x reference)
//
#include <hip/hip_runtime.h>
#include <hip/hip_bf16.h>
#include <math.h>

#define BATCH 64
#define HW 28
#define PIX 784           // 28*28
#define LATENT 256
#define LABEL 10
#define FEAT 50176        // 64*28*28
#define KS 7
#define KCH 7168          // 50176/7

__device__ __forceinline__ float sgnf(float v) {
    return (v > 0.f) ? 1.f : ((v < 0.f) ? -1.f : 0.f);
}

// ---------------------------------------------------------------------------
// Generic 5x5 pad-2 conv (also serves conv-transpose via flipped weights).
// grid = (B, OC), block = 256. in: [B][IC][28][28], out: [B][OC][28][28]
// flip=0: w is [OC][IC][5][5];  flip=1: w is [IC][OC][5][5], use w[ic][oc][4-kh][4-kw]
// ---------------------------------------------------------------------------
__global__ void conv5_k(const float* __restrict__ in, const float* __restrict__ w,
                        const float* __restrict__ bias, float* __restrict__ out,
                        int IC, int OC, int flip, int relu) {
    int b = blockIdx.x, oc = blockIdx.y;
    __shared__ float wl[64 * 25];
    __shared__ float pl[PIX];

    for (int t = threadIdx.x; t < IC * 25; t += 256) {
        int ic = t / 25, k = t % 25;
        wl[t] = flip ? w[(ic * OC + oc) * 25 + (24 - k)]
                     : w[(oc * IC + ic) * 25 + k];
    }

    float acc[4] = {0.f, 0.f, 0.f, 0.f};
    for (int ic = 0; ic < IC; ++ic) {
        __syncthreads();
        for (int t = threadIdx.x; t < PIX; t += 256)
            pl[t] = in[(b * IC + ic) * PIX + t];
        __syncthreads();
        #pragma unroll
        for (int pi = 0; pi < 4; ++pi) {
            int p = threadIdx.x + pi * 256;
            if (p < PIX) {
                int y = p / HW, x = p % HW;
                float a = 0.f;
                #pragma unroll
                for (int dy = 0; dy < 5; ++dy) {
                    int yy = y + dy - 2;
                    if (yy < 0 || yy >= HW) continue;
                    #pragma unroll
                    for (int dx = 0; dx < 5; ++dx) {
                        int xx = x + dx - 2;
                        if (xx < 0 || xx >= HW) continue;
                        a += pl[yy * HW + xx] * wl[ic * 25 + dy * 5 + dx];
                    }
                }
                acc[pi] += a;
            }
        }
    }
    float bv = bias[oc];
    #pragma unroll
    for (int pi = 0; pi < 4; ++pi) {
        int p = threadIdx.x + pi * 256;
        if (p < PIX) {
            float v = acc[pi] + bv;
            if (relu) v = fmaxf(v, 0.f);
            out[(b * OC + oc) * PIX + p] = v;
        }
    }
}

// ---------------------------------------------------------------------------
// Encoder FC partials: z_pre[m][n] = sum_k x[m][k] * w[n][k]
// grid = (64 n-groups of 4, 7 k-chunks), block 256 = 32 k-lanes x 8 m-interleave
// ---------------------------------------------------------------------------
__global__ void enc_fc_part_k(const float* __restrict__ x, const float* __restrict__ w,
                              float* __restrict__ part) {
    int n0 = blockIdx.x * 4;
    int ks = blockIdx.y;
    int kl = threadIdx.x & 31;
    int mi = threadIdx.x >> 5;   // 0..7

    float acc[8][4];
    #pragma unroll
    for (int mg = 0; mg < 8; ++mg)
        #pragma unroll
        for (int nt = 0; nt < 4; ++nt) acc[mg][nt] = 0.f;

    int kend = (ks + 1) * KCH;
    for (int kk = ks * KCH + kl; kk < kend; kk += 32) {
        float xv[8];
        #pragma unroll
        for (int mg = 0; mg < 8; ++mg)
            xv[mg] = x[(mg * 8 + mi) * FEAT + kk];
        #pragma unroll
        for (int nt = 0; nt < 4; ++nt) {
            float wv = w[(n0 + nt) * FEAT + kk];
            #pragma unroll
            for (int mg = 0; mg < 8; ++mg) acc[mg][nt] += xv[mg] * wv;
        }
    }

    #pragma unroll
    for (int mg = 0; mg < 8; ++mg) {
        #pragma unroll
        for (int nt = 0; nt < 4; ++nt) {
            float v = acc[mg][nt];
            v += __shfl_xor(v, 16, 64);
            v += __shfl_xor(v, 8, 64);
            v += __shfl_xor(v, 4, 64);
            v += __shfl_xor(v, 2, 64);
            v += __shfl_xor(v, 1, 64);
            if (kl == 0)
                part[(ks * BATCH + (mg * 8 + mi)) * LATENT + (n0 + nt)] = v;
        }
    }
}

// grid 64 (m), block 256 (n): z = tanh(sum_ks part + b)
__global__ void enc_fc_fin_k(const float* __restrict__ part, const float* __restrict__ bias,
                             float* __restrict__ z) {
    int idx = blockIdx.x * 256 + threadIdx.x;
    int n = idx & 255;
    float a = bias[n];
    for (int ksi = 0; ksi < KS; ++ksi) a += part[ksi * BATCH * LATENT + idx];
    z[idx] = tanhf(a);
}

// ---------------------------------------------------------------------------
// Hopfield weight
// ---------------------------------------------------------------------------
__global__ void hop_rho_k(const float* __restrict__ ll, float* __restrict__ rho_out) {
    float p = 0.f;
    for (int t = threadIdx.x; t < LABEL * LATENT; t += 256) p += sgnf(ll[t]);
    __shared__ float red[8];
    for (int o = 32; o; o >>= 1) p += __shfl_down(p, o, 64);
    if ((threadIdx.x & 63) == 0) red[threadIdx.x >> 6] = p;
    __syncthreads();
    if (threadIdx.x == 0)
        rho_out[0] = (red[0] + red[1] + red[2] + red[3]) / (float)(LABEL * LATENT);
}

__global__ void hop_w_k(const float* __restrict__ ll, const float* __restrict__ rho_p,
                        float* __restrict__ wout) {
    int i = blockIdx.x, j = threadIdx.x;
    float rho = rho_p[0];
    float acc = 0.f;
    #pragma unroll
    for (int l = 0; l < LABEL; ++l) {
        float a = sgnf(ll[l * LATENT + i]) - rho;
        float b = sgnf(ll[l * LATENT + j]) - rho;
        acc += a * b;
    }
    wout[i * LATENT + j] = (i == j) ? 0.f : acc / 10.f;
}

// ---------------------------------------------------------------------------
// Cluster iteration + cluster softmax head. grid 64 (sample), block 256.
// ---------------------------------------------------------------------------
__device__ __forceinline__ float block_sum256(float p, float* red) {
    __syncthreads();
    for (int o = 32; o; o >>= 1) p += __shfl_down(p, o, 64);
    if ((threadIdx.x & 63) == 0) red[threadIdx.x >> 6] = p;
    __syncthreads();
    return red[0] + red[1] + red[2] + red[3];
}

__global__ void cluster_k(const float* __restrict__ z, const float* __restrict__ w,
                          const float* __restrict__ ll, float* __restrict__ out) {
    int b = blockIdx.x;
    int i = threadIdx.x;
    __shared__ float s_sh[LATENT];
    __shared__ float red[8];
    __shared__ float logit[LABEL];

    float zi = z[b * LATENT + i];
    float si = sgnf(zi);
    s_sh[i] = si;
    __syncthreads();

    // v = w @ s (w symmetric: read w[j][i], coalesced over i)
    float v = 0.f;
    for (int j = 0; j < LATENT; ++j) v += w[j * LATENT + i] * s_sh[j];
    float e_prev = -block_sum256(si * v, red);

    for (int it = 0; it < LATENT; ++it) {
        float ns = sgnf(v);
        __syncthreads();
        s_sh[i] = ns;
        __syncthreads();
        float v2 = 0.f;
        for (int j = 0; j < LATENT; ++j) v2 += w[j * LATENT + i] * s_sh[j];
        float e = -block_sum256(ns * v2, red);
        v = v2;
        if (e == e_prev) break;
        e_prev = e;
    }
    // s_sh holds the final clustered state.
    __syncthreads();

    for (int c = 0; c < LABEL; ++c) {
        float p = s_sh[i] * ll[c * LATENT + i];
        float t = block_sum256(p, red);
        if (i == 0) logit[c] = t;
    }
    __syncthreads();
    if (i == 0) {
        float mx = logit[0];
        for (int c = 1; c < LABEL; ++c) mx = fmaxf(mx, logit[c]);
        float ex[LABEL];
        float s = 0.f;
        for (int c = 0; c < LABEL; ++c) { ex[c] = expf(logit[c] - mx); s += ex[c]; }
        for (int c = 0; c < LABEL; ++c) out[b * LABEL + c] = ex[c] / s;
    }
}

// class_probs = softmax(z @ sm_w^T + sm_b). grid 64, block 256.
__global__ void class_k(const float* __restrict__ z, const float* __restrict__ smw,
                        const float* __restrict__ smb, float* __restrict__ out) {
    int b = blockIdx.x;
    int i = threadIdx.x;
    __shared__ float red[8];
    __shared__ float logit[LABEL];
    float zi = z[b * LATENT + i];
    for (int c = 0; c < LABEL; ++c) {
        float p = zi * smw[c * LATENT + i];
        float t = block_sum256(p, red);
        if (i == 0) logit[c] = t + smb[c];
    }
    __syncthreads();
    if (i == 0) {
        float mx = logit[0];
        for (int c = 1; c < LABEL; ++c) mx = fmaxf(mx, logit[c]);
        float ex[LABEL];
        float s = 0.f;
        for (int c = 0; c < LABEL; ++c) { ex[c] = expf(logit[c] - mx); s += ex[c]; }
        for (int c = 0; c < LABEL; ++c) out[b * LABEL + c] = ex[c] / s;
    }
}

// ---------------------------------------------------------------------------
// Decoder FC: y[m][n] = sum_k atanh(z[m][k]) * w[n][k] + b[n]
// grid 196, block 256 (one n per thread).
// ---------------------------------------------------------------------------
__global__ void dec_fc_k(const float* __restrict__ z, const float* __restrict__ w,
                         const float* __restrict__ bias, float* __restrict__ y) {
    __shared__ float xs[16 * LATENT];   // 16 KB
    int n = blockIdx.x * 256 + threadIdx.x;
    float bv = bias[n];
    const float4* wr4 = (const float4*)(w + (size_t)n * LATENT);

    for (int mg = 0; mg < 4; ++mg) {
        __syncthreads();
        for (int t = threadIdx.x; t < 16 * LATENT; t += 256)
            xs[t] = atanhf(z[mg * 16 * LATENT + t]);
        __syncthreads();
        float acc[16];
        #pragma unroll
        for (int r = 0; r < 16; ++r) acc[r] = 0.f;
        for (int k4 = 0; k4 < LATENT / 4; ++k4) {
            float4 wv = wr4[k4];
            int k = k4 * 4;
            #pragma unroll
            for (int r = 0; r < 16; ++r) {
                acc[r] += xs[r * LATENT + k + 0] * wv.x;
                acc[r] += xs[r * LATENT + k + 1] * wv.y;
                acc[r] += xs[r * LATENT + k + 2] * wv.z;
                acc[r] += xs[r * LATENT + k + 3] * wv.w;
            }
        }
        #pragma unroll
        for (int r = 0; r < 16; ++r)
            y[(size_t)(mg * 16 + r) * FEAT + n] = acc[r] + bv;
    }
}

// ---------------------------------------------------------------------------
extern "C" void kernel_launch(void* const* d_in, const int* in_sizes, int n_in,
                              void* d_out, int out_size, void* d_ws, size_t ws_size,
                              hipStream_t stream) {
    const float* images   = (const float*)d_in[0];
    const float* c1w      = (const float*)d_in[1];
    const float* c1b      = (const float*)d_in[2];
    const float* c2w      = (const float*)d_in[3];
    const float* c2b      = (const float*)d_in[4];
    const float* efw      = (const float*)d_in[5];
    const float* efb      = (const float*)d_in[6];
    const float* dfw      = (const float*)d_in[7];
    const float* dfb      = (const float*)d_in[8];
    const float* ct2w     = (const float*)d_in[9];
    const float* ct2b     = (const float*)d_in[10];
    const float* ct1w     = (const float*)d_in[11];
    const float* ct1b     = (const float*)d_in[12];
    const float* smw      = (const float*)d_in[13];
    const float* smb      = (const float*)d_in[14];
    const float* ll       = (const float*)d_in[15];

    float* out = (float*)d_out;
    float* ws  = (float*)d_ws;

    // ws layout (floats)
    float* big0 = ws;                                  // 64*64*784 = 3211264 (a2, later y)
    float* big1 = ws + 3211264;                        // 64*32*784 = 1605632 (a1, later ct2 out)
    float* part = ws + 3211264 + 1605632;              // 7*64*256 = 114688
    float* z    = part + KS * BATCH * LATENT;          // 16384
    float* whop = z + BATCH * LATENT;                  // 65536
    float* rho  = whop + LATENT * LATENT;              // 1

    // encoder
    conv5_k<<<dim3(BATCH, 32), 256, 0, stream>>>(images, c1w, c1b, big1, 1, 32, 0, 1);
    conv5_k<<<dim3(BATCH, 64), 256, 0, stream>>>(big1, c2w, c2b, big0, 32, 64, 0, 1);
    enc_fc_part_k<<<dim3(64, KS), 256, 0, stream>>>(big0, efw, part);
    enc_fc_fin_k<<<BATCH, 256, 0, stream>>>(part, efb, z);

    // hopfield
    hop_rho_k<<<1, 256, 0, stream>>>(ll, rho);
    hop_w_k<<<LATENT, 256, 0, stream>>>(ll, rho, whop);
    cluster_k<<<BATCH, 256, 0, stream>>>(z, whop, ll, out);            // cluster_probs
    class_k<<<BATCH, 256, 0, stream>>>(z, smw, smb, out + 640);        // class_probs

    // decoder
    dec_fc_k<<<FEAT / 256, 256, 0, stream>>>(z, dfw, dfb, big0);
    conv5_k<<<dim3(BATCH, 32), 256, 0, stream>>>(big0, ct2w, ct2b, big1, 64, 32, 1, 1);
    conv5_k<<<dim3(BATCH, 1), 256, 0, stream>>>(big1, ct1w, ct1b, out + 1280, 32, 1, 1, 0);
}

// Round 2
// 1426.045 us; speedup vs baseline: 1.6034x; 1.6034x over previous
//
#include <hip/hip_runtime.h>
#include <hip/hip_bf16.h>
#include <math.h>

#define BATCH 64
#define HW 28
#define PIX 784           // 28*28
#define LATENT 256
#define LABEL 10
#define FEAT 50176        // 64*28*28
#define KS 7
#define KCH 7168          // 50176/7

__device__ __forceinline__ float sgnf(float v) {
    return (v > 0.f) ? 1.f : ((v < 0.f) ? -1.f : 0.f);
}

// ---------------------------------------------------------------------------
// Generic 5x5 pad-2 conv (also serves conv-transpose via flipped weights).
// grid = (B, OC), block = 256. in: [B][IC][28][28], out: [B][OC][28][28]
// flip=0: w is [OC][IC][5][5];  flip=1: w is [IC][OC][5][5], use w[ic][oc][4-kh][4-kw]
// ---------------------------------------------------------------------------
__global__ void conv5_k(const float* __restrict__ in, const float* __restrict__ w,
                        const float* __restrict__ bias, float* __restrict__ out,
                        int IC, int OC, int flip, int relu) {
    int b = blockIdx.x, oc = blockIdx.y;
    __shared__ float wl[64 * 25];
    __shared__ float pl[PIX];

    for (int t = threadIdx.x; t < IC * 25; t += 256) {
        int ic = t / 25, k = t % 25;
        wl[t] = flip ? w[(ic * OC + oc) * 25 + (24 - k)]
                     : w[(oc * IC + ic) * 25 + k];
    }

    float acc[4] = {0.f, 0.f, 0.f, 0.f};
    for (int ic = 0; ic < IC; ++ic) {
        __syncthreads();
        for (int t = threadIdx.x; t < PIX; t += 256)
            pl[t] = in[(b * IC + ic) * PIX + t];
        __syncthreads();
        #pragma unroll
        for (int pi = 0; pi < 4; ++pi) {
            int p = threadIdx.x + pi * 256;
            if (p < PIX) {
                int y = p / HW, x = p % HW;
                float a = 0.f;
                #pragma unroll
                for (int dy = 0; dy < 5; ++dy) {
                    int yy = y + dy - 2;
                    if (yy < 0 || yy >= HW) continue;
                    #pragma unroll
                    for (int dx = 0; dx < 5; ++dx) {
                        int xx = x + dx - 2;
                        if (xx < 0 || xx >= HW) continue;
                        a += pl[yy * HW + xx] * wl[ic * 25 + dy * 5 + dx];
                    }
                }
                acc[pi] += a;
            }
        }
    }
    float bv = bias[oc];
    #pragma unroll
    for (int pi = 0; pi < 4; ++pi) {
        int p = threadIdx.x + pi * 256;
        if (p < PIX) {
            float v = acc[pi] + bv;
            if (relu) v = fmaxf(v, 0.f);
            out[(b * OC + oc) * PIX + p] = v;
        }
    }
}

// ---------------------------------------------------------------------------
// Encoder FC partials: z_pre[m][n] = sum_k x[m][k] * w[n][k]
// ---------------------------------------------------------------------------
__global__ void enc_fc_part_k(const float* __restrict__ x, const float* __restrict__ w,
                              float* __restrict__ part) {
    int n0 = blockIdx.x * 4;
    int ks = blockIdx.y;
    int kl = threadIdx.x & 31;
    int mi = threadIdx.x >> 5;   // 0..7

    float acc[8][4];
    #pragma unroll
    for (int mg = 0; mg < 8; ++mg)
        #pragma unroll
        for (int nt = 0; nt < 4; ++nt) acc[mg][nt] = 0.f;

    int kend = (ks + 1) * KCH;
    for (int kk = ks * KCH + kl; kk < kend; kk += 32) {
        float xv[8];
        #pragma unroll
        for (int mg = 0; mg < 8; ++mg)
            xv[mg] = x[(mg * 8 + mi) * FEAT + kk];
        #pragma unroll
        for (int nt = 0; nt < 4; ++nt) {
            float wv = w[(n0 + nt) * FEAT + kk];
            #pragma unroll
            for (int mg = 0; mg < 8; ++mg) acc[mg][nt] += xv[mg] * wv;
        }
    }

    #pragma unroll
    for (int mg = 0; mg < 8; ++mg) {
        #pragma unroll
        for (int nt = 0; nt < 4; ++nt) {
            float v = acc[mg][nt];
            v += __shfl_xor(v, 16, 64);
            v += __shfl_xor(v, 8, 64);
            v += __shfl_xor(v, 4, 64);
            v += __shfl_xor(v, 2, 64);
            v += __shfl_xor(v, 1, 64);
            if (kl == 0)
                part[(ks * BATCH + (mg * 8 + mi)) * LATENT + (n0 + nt)] = v;
        }
    }
}

// grid 64 (m), block 256 (n): z = tanh(sum_ks part + b)
__global__ void enc_fc_fin_k(const float* __restrict__ part, const float* __restrict__ bias,
                             float* __restrict__ z) {
    int idx = blockIdx.x * 256 + threadIdx.x;
    int n = idx & 255;
    float a = bias[n];
    for (int ksi = 0; ksi < KS; ++ksi) a += part[ksi * BATCH * LATENT + idx];
    z[idx] = tanhf(a);
}

// ---------------------------------------------------------------------------
// Hopfield weight
// ---------------------------------------------------------------------------
__global__ void hop_rho_k(const float* __restrict__ ll, float* __restrict__ rho_out) {
    float p = 0.f;
    for (int t = threadIdx.x; t < LABEL * LATENT; t += 256) p += sgnf(ll[t]);
    __shared__ float red[8];
    for (int o = 32; o; o >>= 1) p += __shfl_down(p, o, 64);
    if ((threadIdx.x & 63) == 0) red[threadIdx.x >> 6] = p;
    __syncthreads();
    if (threadIdx.x == 0)
        rho_out[0] = (red[0] + red[1] + red[2] + red[3]) / (float)(LABEL * LATENT);
}

__global__ void hop_w_k(const float* __restrict__ ll, const float* __restrict__ rho_p,
                        float* __restrict__ wout) {
    int i = blockIdx.x, j = threadIdx.x;
    float rho = rho_p[0];
    float acc = 0.f;
    #pragma unroll
    for (int l = 0; l < LABEL; ++l) {
        float a = sgnf(ll[l * LATENT + i]) - rho;
        float b = sgnf(ll[l * LATENT + j]) - rho;
        acc += a * b;
    }
    wout[i * LATENT + j] = (i == j) ? 0.f : acc / 10.f;
}

// ---------------------------------------------------------------------------
// Cluster iteration + cluster softmax head.
// grid 64 (sample), block 1024 = 4 j-quarters x 256 i.
// Thread (q,i) holds w[(q*64+jj)*256+i] in registers (fully unrolled).
// Per iteration: 64-FMA partial matvec -> LDS combine -> sign -> energy reduce.
// Early exit: (a) e == e_prev (exact reference semantics, checked first);
// (b) 2-cycle detection state_{t+1}==state_{t-1} -> final state by parity of
// remaining scan steps (energies alternate, done never fires -> identical
// output to running the full 256-step scan).
// ---------------------------------------------------------------------------
__global__ __launch_bounds__(1024) void cluster_k(const float* __restrict__ z,
                          const float* __restrict__ w,
                          const float* __restrict__ ll, float* __restrict__ out) {
    int b = blockIdx.x;
    int t = threadIdx.x;
    int i = t & 255;
    int q = t >> 8;           // 0..3 (j-quarter)
    int lane = t & 63;
    int wvid = t >> 6;        // wave 0..15

    __shared__ float s_sh[LATENT];
    __shared__ float part[1024];
    __shared__ float red[4];
    __shared__ float cflag[4];
    __shared__ int ctl_sh;
    __shared__ float logit[LABEL];

    float wreg[64];
    #pragma unroll
    for (int jj = 0; jj < 64; ++jj)
        wreg[jj] = w[(q * 64 + jj) * LATENT + i];

    float s_cur = 0.f, s_old = 2.f, v = 0.f;
    float e_prev = 0.f;       // live on thread 0 only
    if (q == 0) {
        s_cur = sgnf(z[b * LATENT + i]);
        s_sh[i] = s_cur;
    }
    __syncthreads();

    // prologue: v = w @ s0, e_prev = energy(s0)
    {
        float p0 = 0.f, p1 = 0.f;
        #pragma unroll
        for (int jj = 0; jj < 64; jj += 2) {
            p0 += wreg[jj]     * s_sh[q * 64 + jj];
            p1 += wreg[jj + 1] * s_sh[q * 64 + jj + 1];
        }
        part[t] = p0 + p1;
    }
    __syncthreads();
    if (q == 0) {
        v = part[i] + part[i + 256] + part[i + 512] + part[i + 768];
        float p = s_cur * v;
        #pragma unroll
        for (int o = 32; o; o >>= 1) p += __shfl_down(p, o, 64);
        if (lane == 0) red[wvid] = p;
    }
    __syncthreads();
    if (t == 0) e_prev = -(red[0] + red[1] + red[2] + red[3]);

    for (int it = 0; it < LATENT; ++it) {
        if (q == 0) {
            float ns = sgnf(v);                       // state_{it+1}
            unsigned long long m = __ballot(ns == s_old);  // vs state_{it-1}
            if (lane == 0) cflag[wvid] = (m == ~0ull) ? 1.f : 0.f;
            s_sh[i] = ns;
            s_old = s_cur;
            s_cur = ns;
        }
        __syncthreads();
        {
            float p0 = 0.f, p1 = 0.f;
            #pragma unroll
            for (int jj = 0; jj < 64; jj += 2) {
                p0 += wreg[jj]     * s_sh[q * 64 + jj];
                p1 += wreg[jj + 1] * s_sh[q * 64 + jj + 1];
            }
            part[t] = p0 + p1;
        }
        __syncthreads();
        if (q == 0) {
            v = part[i] + part[i + 256] + part[i + 512] + part[i + 768];
            float p = s_cur * v;                      // energy(new state) terms
            #pragma unroll
            for (int o = 32; o; o >>= 1) p += __shfl_down(p, o, 64);
            if (lane == 0) red[wvid] = p;
        }
        __syncthreads();
        if (t == 0) {
            float e = -(red[0] + red[1] + red[2] + red[3]);
            int c = 0;
            if (e == e_prev) c = 1;                   // reference done-fires: keep ns
            else if (it >= 1 && cflag[0] != 0.f && cflag[1] != 0.f &&
                     cflag[2] != 0.f && cflag[3] != 0.f)
                c = (((LATENT - 1 - it) & 1) == 0) ? 2 : 3;  // 2-cycle parity
            else e_prev = e;
            ctl_sh = c;
        }
        __syncthreads();
        int c = ctl_sh;
        if (c != 0) {
            if (c == 3 && q == 0) s_sh[i] = s_old;    // odd remaining: prior state
            break;
        }
    }
    __syncthreads();

    // logits: wave c (c<10) computes clustered . ll[c]
    if (wvid < LABEL) {
        float p = 0.f;
        #pragma unroll
        for (int r = 0; r < 4; ++r)
            p += s_sh[r * 64 + lane] * ll[wvid * LATENT + r * 64 + lane];
        #pragma unroll
        for (int o = 32; o; o >>= 1) p += __shfl_down(p, o, 64);
        if (lane == 0) logit[wvid] = p;
    }
    __syncthreads();
    if (t == 0) {
        float mx = logit[0];
        for (int c = 1; c < LABEL; ++c) mx = fmaxf(mx, logit[c]);
        float ex[LABEL];
        float s = 0.f;
        for (int c = 0; c < LABEL; ++c) { ex[c] = expf(logit[c] - mx); s += ex[c]; }
        for (int c = 0; c < LABEL; ++c) out[b * LABEL + c] = ex[c] / s;
    }
}

// class_probs = softmax(z @ sm_w^T + sm_b). grid 64, block 256.
__device__ __forceinline__ float block_sum256(float p, float* red) {
    __syncthreads();
    for (int o = 32; o; o >>= 1) p += __shfl_down(p, o, 64);
    if ((threadIdx.x & 63) == 0) red[threadIdx.x >> 6] = p;
    __syncthreads();
    return red[0] + red[1] + red[2] + red[3];
}

__global__ void class_k(const float* __restrict__ z, const float* __restrict__ smw,
                        const float* __restrict__ smb, float* __restrict__ out) {
    int b = blockIdx.x;
    int i = threadIdx.x;
    __shared__ float red[8];
    __shared__ float logit[LABEL];
    float zi = z[b * LATENT + i];
    for (int c = 0; c < LABEL; ++c) {
        float p = zi * smw[c * LATENT + i];
        float t = block_sum256(p, red);
        if (i == 0) logit[c] = t + smb[c];
    }
    __syncthreads();
    if (i == 0) {
        float mx = logit[0];
        for (int c = 1; c < LABEL; ++c) mx = fmaxf(mx, logit[c]);
        float ex[LABEL];
        float s = 0.f;
        for (int c = 0; c < LABEL; ++c) { ex[c] = expf(logit[c] - mx); s += ex[c]; }
        for (int c = 0; c < LABEL; ++c) out[b * LABEL + c] = ex[c] / s;
    }
}

// ---------------------------------------------------------------------------
// Decoder FC: y[m][n] = sum_k atanh(z[m][k]) * w[n][k] + b[n]
// grid 196, block 256 (one n per thread).
// ---------------------------------------------------------------------------
__global__ void dec_fc_k(const float* __restrict__ z, const float* __restrict__ w,
                         const float* __restrict__ bias, float* __restrict__ y) {
    __shared__ float xs[16 * LATENT];   // 16 KB
    int n = blockIdx.x * 256 + threadIdx.x;
    float bv = bias[n];
    const float4* wr4 = (const float4*)(w + (size_t)n * LATENT);

    for (int mg = 0; mg < 4; ++mg) {
        __syncthreads();
        for (int t = threadIdx.x; t < 16 * LATENT; t += 256)
            xs[t] = atanhf(z[mg * 16 * LATENT + t]);
        __syncthreads();
        float acc[16];
        #pragma unroll
        for (int r = 0; r < 16; ++r) acc[r] = 0.f;
        for (int k4 = 0; k4 < LATENT / 4; ++k4) {
            float4 wv = wr4[k4];
            int k = k4 * 4;
            #pragma unroll
            for (int r = 0; r < 16; ++r) {
                acc[r] += xs[r * LATENT + k + 0] * wv.x;
                acc[r] += xs[r * LATENT + k + 1] * wv.y;
                acc[r] += xs[r * LATENT + k + 2] * wv.z;
                acc[r] += xs[r * LATENT + k + 3] * wv.w;
            }
        }
        #pragma unroll
        for (int r = 0; r < 16; ++r)
            y[(size_t)(mg * 16 + r) * FEAT + n] = acc[r] + bv;
    }
}

// ---------------------------------------------------------------------------
extern "C" void kernel_launch(void* const* d_in, const int* in_sizes, int n_in,
                              void* d_out, int out_size, void* d_ws, size_t ws_size,
                              hipStream_t stream) {
    const float* images   = (const float*)d_in[0];
    const float* c1w      = (const float*)d_in[1];
    const float* c1b      = (const float*)d_in[2];
    const float* c2w      = (const float*)d_in[3];
    const float* c2b      = (const float*)d_in[4];
    const float* efw      = (const float*)d_in[5];
    const float* efb      = (const float*)d_in[6];
    const float* dfw      = (const float*)d_in[7];
    const float* dfb      = (const float*)d_in[8];
    const float* ct2w     = (const float*)d_in[9];
    const float* ct2b     = (const float*)d_in[10];
    const float* ct1w     = (const float*)d_in[11];
    const float* ct1b     = (const float*)d_in[12];
    const float* smw      = (const float*)d_in[13];
    const float* smb      = (const float*)d_in[14];
    const float* ll       = (const float*)d_in[15];

    float* out = (float*)d_out;
    float* ws  = (float*)d_ws;

    // ws layout (floats)
    float* big0 = ws;                                  // 64*64*784 = 3211264 (a2, later y)
    float* big1 = ws + 3211264;                        // 64*32*784 = 1605632 (a1, later ct2 out)
    float* part = ws + 3211264 + 1605632;              // 7*64*256 = 114688
    float* z    = part + KS * BATCH * LATENT;          // 16384
    float* whop = z + BATCH * LATENT;                  // 65536
    float* rho  = whop + LATENT * LATENT;              // 1

    // encoder
    conv5_k<<<dim3(BATCH, 32), 256, 0, stream>>>(images, c1w, c1b, big1, 1, 32, 0, 1);
    conv5_k<<<dim3(BATCH, 64), 256, 0, stream>>>(big1, c2w, c2b, big0, 32, 64, 0, 1);
    enc_fc_part_k<<<dim3(64, KS), 256, 0, stream>>>(big0, efw, part);
    enc_fc_fin_k<<<BATCH, 256, 0, stream>>>(part, efb, z);

    // hopfield
    hop_rho_k<<<1, 256, 0, stream>>>(ll, rho);
    hop_w_k<<<LATENT, 256, 0, stream>>>(ll, rho, whop);
    cluster_k<<<BATCH, 1024, 0, stream>>>(z, whop, ll, out);           // cluster_probs
    class_k<<<BATCH, 256, 0, stream>>>(z, smw, smb, out + 640);        // class_probs

    // decoder
    dec_fc_k<<<FEAT / 256, 256, 0, stream>>>(z, dfw, dfb, big0);
    conv5_k<<<dim3(BATCH, 32), 256, 0, stream>>>(big0, ct2w, ct2b, big1, 64, 32, 1, 1);
    conv5_k<<<dim3(BATCH, 1), 256, 0, stream>>>(big1, ct1w, ct1b, out + 1280, 32, 1, 1, 0);
}

// Round 3
// 556.438 us; speedup vs baseline: 4.1092x; 2.5628x over previous
//
#include <hip/hip_runtime.h>
#include <hip/hip_bf16.h>
#include <math.h>

#define BATCH 64
#define HW 28
#define PIX 784           // 28*28
#define LATENT 256
#define LABEL 10
#define FEAT 50176        // 64*28*28
#define KS 7
#define KCH 7168          // 50176/7

__device__ __forceinline__ float sgnf(float v) {
    return (v > 0.f) ? 1.f : ((v < 0.f) ? -1.f : 0.f);
}

// ---------------------------------------------------------------------------
// 5x5 pad-2 conv, register-blocked. Serves conv-transpose via FLIP template.
// grid = (B, OC/G), block = 256. in: [B][IC][28][28], out: [B][OC][28][28]
// Thread (y, xg) owns a 1x4 output strip for G output channels.
// Input staged per-ic into a zero-padded 32x32 LDS tile (+2 shift both axes):
// no bounds checks, aligned float4 LDS reads. Weights are uniform-indexed
// global loads (scalarized to s_load by the compiler).
// FLIP=0: w[OC][IC][5][5];  FLIP=1: w[IC][OC][5][5] with kernel rotation.
// ---------------------------------------------------------------------------
template<int G, int FLIP>
__global__ __launch_bounds__(256) void conv5_k(const float* __restrict__ in,
                        const float* __restrict__ w,
                        const float* __restrict__ bias, float* __restrict__ out,
                        int IC, int OC, int relu) {
    int b = blockIdx.x, oc0 = blockIdx.y * G;
    __shared__ float plp[32][32];   // 4 KB padded tile
    int tid = threadIdx.x;

    // zero the tile once (borders persist across ic iterations)
    *(float4*)&((float*)plp)[tid * 4] = make_float4(0.f, 0.f, 0.f, 0.f);

    bool act = tid < 196;
    int y = tid / 7, q = tid % 7, x0 = q * 4;

    float acc[G][4];
    #pragma unroll
    for (int g = 0; g < G; ++g)
        #pragma unroll
        for (int xi = 0; xi < 4; ++xi) acc[g][xi] = 0.f;

    for (int ic = 0; ic < IC; ++ic) {
        __syncthreads();
        if (act) {
            // contiguous: element offset = 4*tid (since 28*y/7... = 4*tid)
            float4 v = *(const float4*)&in[((size_t)(b * IC + ic)) * PIX + tid * 4];
            *(float2*)&plp[y + 2][4 * q + 2] = make_float2(v.x, v.y);
            *(float2*)&plp[y + 2][4 * q + 4] = make_float2(v.z, v.w);
        }
        __syncthreads();
        if (act) {
            #pragma unroll
            for (int dy = 0; dy < 5; ++dy) {
                float4 ra = *(float4*)&plp[y + dy][x0];
                float4 rb = *(float4*)&plp[y + dy][x0 + 4];
                float rw[8] = {ra.x, ra.y, ra.z, ra.w, rb.x, rb.y, rb.z, rb.w};
                #pragma unroll
                for (int g = 0; g < G; ++g) {
                    #pragma unroll
                    for (int dx = 0; dx < 5; ++dx) {
                        float wv = FLIP
                            ? w[((size_t)ic * OC + (oc0 + g)) * 25 + (4 - dy) * 5 + (4 - dx)]
                            : w[((size_t)(oc0 + g) * IC + ic) * 25 + dy * 5 + dx];
                        #pragma unroll
                        for (int xi = 0; xi < 4; ++xi)
                            acc[g][xi] += rw[xi + dx] * wv;
                    }
                }
            }
        }
    }
    if (act) {
        #pragma unroll
        for (int g = 0; g < G; ++g) {
            float bv = bias[oc0 + g];
            float4 o;
            o.x = acc[g][0] + bv;
            o.y = acc[g][1] + bv;
            o.z = acc[g][2] + bv;
            o.w = acc[g][3] + bv;
            if (relu) {
                o.x = fmaxf(o.x, 0.f); o.y = fmaxf(o.y, 0.f);
                o.z = fmaxf(o.z, 0.f); o.w = fmaxf(o.w, 0.f);
            }
            *(float4*)&out[((size_t)(b * OC + (oc0 + g))) * PIX + y * HW + x0] = o;
        }
    }
}

// ---------------------------------------------------------------------------
// Encoder FC partials: z_pre[m][n] = sum_k x[m][k] * w[n][k]
// ---------------------------------------------------------------------------
__global__ void enc_fc_part_k(const float* __restrict__ x, const float* __restrict__ w,
                              float* __restrict__ part) {
    int n0 = blockIdx.x * 4;
    int ks = blockIdx.y;
    int kl = threadIdx.x & 31;
    int mi = threadIdx.x >> 5;   // 0..7

    float acc[8][4];
    #pragma unroll
    for (int mg = 0; mg < 8; ++mg)
        #pragma unroll
        for (int nt = 0; nt < 4; ++nt) acc[mg][nt] = 0.f;

    int kend = (ks + 1) * KCH;
    for (int kk = ks * KCH + kl; kk < kend; kk += 32) {
        float xv[8];
        #pragma unroll
        for (int mg = 0; mg < 8; ++mg)
            xv[mg] = x[(mg * 8 + mi) * FEAT + kk];
        #pragma unroll
        for (int nt = 0; nt < 4; ++nt) {
            float wv = w[(n0 + nt) * FEAT + kk];
            #pragma unroll
            for (int mg = 0; mg < 8; ++mg) acc[mg][nt] += xv[mg] * wv;
        }
    }

    #pragma unroll
    for (int mg = 0; mg < 8; ++mg) {
        #pragma unroll
        for (int nt = 0; nt < 4; ++nt) {
            float v = acc[mg][nt];
            v += __shfl_xor(v, 16, 64);
            v += __shfl_xor(v, 8, 64);
            v += __shfl_xor(v, 4, 64);
            v += __shfl_xor(v, 2, 64);
            v += __shfl_xor(v, 1, 64);
            if (kl == 0)
                part[(ks * BATCH + (mg * 8 + mi)) * LATENT + (n0 + nt)] = v;
        }
    }
}

// grid 64 (m), block 256 (n): z = tanh(sum_ks part + b)
__global__ void enc_fc_fin_k(const float* __restrict__ part, const float* __restrict__ bias,
                             float* __restrict__ z) {
    int idx = blockIdx.x * 256 + threadIdx.x;
    int n = idx & 255;
    float a = bias[n];
    for (int ksi = 0; ksi < KS; ++ksi) a += part[ksi * BATCH * LATENT + idx];
    z[idx] = tanhf(a);
}

// ---------------------------------------------------------------------------
// Hopfield weight
// ---------------------------------------------------------------------------
__global__ void hop_rho_k(const float* __restrict__ ll, float* __restrict__ rho_out) {
    float p = 0.f;
    for (int t = threadIdx.x; t < LABEL * LATENT; t += 256) p += sgnf(ll[t]);
    __shared__ float red[8];
    for (int o = 32; o; o >>= 1) p += __shfl_down(p, o, 64);
    if ((threadIdx.x & 63) == 0) red[threadIdx.x >> 6] = p;
    __syncthreads();
    if (threadIdx.x == 0)
        rho_out[0] = (red[0] + red[1] + red[2] + red[3]) / (float)(LABEL * LATENT);
}

__global__ void hop_w_k(const float* __restrict__ ll, const float* __restrict__ rho_p,
                        float* __restrict__ wout) {
    int i = blockIdx.x, j = threadIdx.x;
    float rho = rho_p[0];
    float acc = 0.f;
    #pragma unroll
    for (int l = 0; l < LABEL; ++l) {
        float a = sgnf(ll[l * LATENT + i]) - rho;
        float b = sgnf(ll[l * LATENT + j]) - rho;
        acc += a * b;
    }
    wout[i * LATENT + j] = (i == j) ? 0.f : acc / 10.f;
}

// ---------------------------------------------------------------------------
// Cluster iteration + cluster softmax head.
// grid 64 (sample), block 1024 = 4 j-quarters x 256 i.
// ---------------------------------------------------------------------------
__global__ __launch_bounds__(1024) void cluster_k(const float* __restrict__ z,
                          const float* __restrict__ w,
                          const float* __restrict__ ll, float* __restrict__ out) {
    int b = blockIdx.x;
    int t = threadIdx.x;
    int i = t & 255;
    int q = t >> 8;           // 0..3 (j-quarter)
    int lane = t & 63;
    int wvid = t >> 6;        // wave 0..15

    __shared__ float s_sh[LATENT];
    __shared__ float part[1024];
    __shared__ float red[4];
    __shared__ float cflag[4];
    __shared__ int ctl_sh;
    __shared__ float logit[LABEL];

    float wreg[64];
    #pragma unroll
    for (int jj = 0; jj < 64; ++jj)
        wreg[jj] = w[(q * 64 + jj) * LATENT + i];

    float s_cur = 0.f, s_old = 2.f, v = 0.f;
    float e_prev = 0.f;       // live on thread 0 only
    if (q == 0) {
        s_cur = sgnf(z[b * LATENT + i]);
        s_sh[i] = s_cur;
    }
    __syncthreads();

    // prologue: v = w @ s0, e_prev = energy(s0)
    {
        float p0 = 0.f, p1 = 0.f;
        #pragma unroll
        for (int jj = 0; jj < 64; jj += 2) {
            p0 += wreg[jj]     * s_sh[q * 64 + jj];
            p1 += wreg[jj + 1] * s_sh[q * 64 + jj + 1];
        }
        part[t] = p0 + p1;
    }
    __syncthreads();
    if (q == 0) {
        v = part[i] + part[i + 256] + part[i + 512] + part[i + 768];
        float p = s_cur * v;
        #pragma unroll
        for (int o = 32; o; o >>= 1) p += __shfl_down(p, o, 64);
        if (lane == 0) red[wvid] = p;
    }
    __syncthreads();
    if (t == 0) e_prev = -(red[0] + red[1] + red[2] + red[3]);

    for (int it = 0; it < LATENT; ++it) {
        if (q == 0) {
            float ns = sgnf(v);                       // state_{it+1}
            unsigned long long m = __ballot(ns == s_old);  // vs state_{it-1}
            if (lane == 0) cflag[wvid] = (m == ~0ull) ? 1.f : 0.f;
            s_sh[i] = ns;
            s_old = s_cur;
            s_cur = ns;
        }
        __syncthreads();
        {
            float p0 = 0.f, p1 = 0.f;
            #pragma unroll
            for (int jj = 0; jj < 64; jj += 2) {
                p0 += wreg[jj]     * s_sh[q * 64 + jj];
                p1 += wreg[jj + 1] * s_sh[q * 64 + jj + 1];
            }
            part[t] = p0 + p1;
        }
        __syncthreads();
        if (q == 0) {
            v = part[i] + part[i + 256] + part[i + 512] + part[i + 768];
            float p = s_cur * v;                      // energy(new state) terms
            #pragma unroll
            for (int o = 32; o; o >>= 1) p += __shfl_down(p, o, 64);
            if (lane == 0) red[wvid] = p;
        }
        __syncthreads();
        if (t == 0) {
            float e = -(red[0] + red[1] + red[2] + red[3]);
            int c = 0;
            if (e == e_prev) c = 1;                   // reference done-fires: keep ns
            else if (it >= 1 && cflag[0] != 0.f && cflag[1] != 0.f &&
                     cflag[2] != 0.f && cflag[3] != 0.f)
                c = (((LATENT - 1 - it) & 1) == 0) ? 2 : 3;  // 2-cycle parity
            else e_prev = e;
            ctl_sh = c;
        }
        __syncthreads();
        int c = ctl_sh;
        if (c != 0) {
            if (c == 3 && q == 0) s_sh[i] = s_old;    // odd remaining: prior state
            break;
        }
    }
    __syncthreads();

    // logits: wave c (c<10) computes clustered . ll[c]
    if (wvid < LABEL) {
        float p = 0.f;
        #pragma unroll
        for (int r = 0; r < 4; ++r)
            p += s_sh[r * 64 + lane] * ll[wvid * LATENT + r * 64 + lane];
        #pragma unroll
        for (int o = 32; o; o >>= 1) p += __shfl_down(p, o, 64);
        if (lane == 0) logit[wvid] = p;
    }
    __syncthreads();
    if (t == 0) {
        float mx = logit[0];
        for (int c = 1; c < LABEL; ++c) mx = fmaxf(mx, logit[c]);
        float ex[LABEL];
        float s = 0.f;
        for (int c = 0; c < LABEL; ++c) { ex[c] = expf(logit[c] - mx); s += ex[c]; }
        for (int c = 0; c < LABEL; ++c) out[b * LABEL + c] = ex[c] / s;
    }
}

// class_probs = softmax(z @ sm_w^T + sm_b). grid 64, block 256.
__device__ __forceinline__ float block_sum256(float p, float* red) {
    __syncthreads();
    for (int o = 32; o; o >>= 1) p += __shfl_down(p, o, 64);
    if ((threadIdx.x & 63) == 0) red[threadIdx.x >> 6] = p;
    __syncthreads();
    return red[0] + red[1] + red[2] + red[3];
}

__global__ void class_k(const float* __restrict__ z, const float* __restrict__ smw,
                        const float* __restrict__ smb, float* __restrict__ out) {
    int b = blockIdx.x;
    int i = threadIdx.x;
    __shared__ float red[8];
    __shared__ float logit[LABEL];
    float zi = z[b * LATENT + i];
    for (int c = 0; c < LABEL; ++c) {
        float p = zi * smw[c * LATENT + i];
        float t = block_sum256(p, red);
        if (i == 0) logit[c] = t + smb[c];
    }
    __syncthreads();
    if (i == 0) {
        float mx = logit[0];
        for (int c = 1; c < LABEL; ++c) mx = fmaxf(mx, logit[c]);
        float ex[LABEL];
        float s = 0.f;
        for (int c = 0; c < LABEL; ++c) { ex[c] = expf(logit[c] - mx); s += ex[c]; }
        for (int c = 0; c < LABEL; ++c) out[b * LABEL + c] = ex[c] / s;
    }
}

// ---------------------------------------------------------------------------
// Decoder FC: y[m][n] = sum_k atanh(z[m][k]) * w[n][k] + b[n]
// grid 196, block 256 (one n per thread).
// ---------------------------------------------------------------------------
__global__ void dec_fc_k(const float* __restrict__ z, const float* __restrict__ w,
                         const float* __restrict__ bias, float* __restrict__ y) {
    __shared__ float xs[16 * LATENT];   // 16 KB
    int n = blockIdx.x * 256 + threadIdx.x;
    float bv = bias[n];
    const float4* wr4 = (const float4*)(w + (size_t)n * LATENT);

    for (int mg = 0; mg < 4; ++mg) {
        __syncthreads();
        for (int t = threadIdx.x; t < 16 * LATENT; t += 256)
            xs[t] = atanhf(z[mg * 16 * LATENT + t]);
        __syncthreads();
        float acc[16];
        #pragma unroll
        for (int r = 0; r < 16; ++r) acc[r] = 0.f;
        for (int k4 = 0; k4 < LATENT / 4; ++k4) {
            float4 wv = wr4[k4];
            int k = k4 * 4;
            #pragma unroll
            for (int r = 0; r < 16; ++r) {
                acc[r] += xs[r * LATENT + k + 0] * wv.x;
                acc[r] += xs[r * LATENT + k + 1] * wv.y;
                acc[r] += xs[r * LATENT + k + 2] * wv.z;
                acc[r] += xs[r * LATENT + k + 3] * wv.w;
            }
        }
        #pragma unroll
        for (int r = 0; r < 16; ++r)
            y[(size_t)(mg * 16 + r) * FEAT + n] = acc[r] + bv;
    }
}

// ---------------------------------------------------------------------------
extern "C" void kernel_launch(void* const* d_in, const int* in_sizes, int n_in,
                              void* d_out, int out_size, void* d_ws, size_t ws_size,
                              hipStream_t stream) {
    const float* images   = (const float*)d_in[0];
    const float* c1w      = (const float*)d_in[1];
    const float* c1b      = (const float*)d_in[2];
    const float* c2w      = (const float*)d_in[3];
    const float* c2b      = (const float*)d_in[4];
    const float* efw      = (const float*)d_in[5];
    const float* efb      = (const float*)d_in[6];
    const float* dfw      = (const float*)d_in[7];
    const float* dfb      = (const float*)d_in[8];
    const float* ct2w     = (const float*)d_in[9];
    const float* ct2b     = (const float*)d_in[10];
    const float* ct1w     = (const float*)d_in[11];
    const float* ct1b     = (const float*)d_in[12];
    const float* smw      = (const float*)d_in[13];
    const float* smb      = (const float*)d_in[14];
    const float* ll       = (const float*)d_in[15];

    float* out = (float*)d_out;
    float* ws  = (float*)d_ws;

    // ws layout (floats)
    float* big0 = ws;                                  // 64*64*784 = 3211264 (a2, later y)
    float* big1 = ws + 3211264;                        // 64*32*784 = 1605632 (a1, later ct2 out)
    float* part = ws + 3211264 + 1605632;              // 7*64*256 = 114688
    float* z    = part + KS * BATCH * LATENT;          // 16384
    float* whop = z + BATCH * LATENT;                  // 65536
    float* rho  = whop + LATENT * LATENT;              // 1

    // encoder
    conv5_k<4,0><<<dim3(BATCH, 8), 256, 0, stream>>>(images, c1w, c1b, big1, 1, 32, 1);
    conv5_k<4,0><<<dim3(BATCH, 16), 256, 0, stream>>>(big1, c2w, c2b, big0, 32, 64, 1);
    enc_fc_part_k<<<dim3(64, KS), 256, 0, stream>>>(big0, efw, part);
    enc_fc_fin_k<<<BATCH, 256, 0, stream>>>(part, efb, z);

    // hopfield
    hop_rho_k<<<1, 256, 0, stream>>>(ll, rho);
    hop_w_k<<<LATENT, 256, 0, stream>>>(ll, rho, whop);
    cluster_k<<<BATCH, 1024, 0, stream>>>(z, whop, ll, out);           // cluster_probs
    class_k<<<BATCH, 256, 0, stream>>>(z, smw, smb, out + 640);        // class_probs

    // decoder
    dec_fc_k<<<FEAT / 256, 256, 0, stream>>>(z, dfw, dfb, big0);
    conv5_k<4,1><<<dim3(BATCH, 8), 256, 0, stream>>>(big0, ct2w, ct2b, big1, 64, 32, 1);
    conv5_k<1,1><<<dim3(BATCH, 1), 256, 0, stream>>>(big1, ct1w, ct1b, out + 1280, 32, 1, 0);
}

// Round 4
// 526.997 us; speedup vs baseline: 4.3388x; 1.0559x over previous
//
#include <hip/hip_runtime.h>
#include <hip/hip_bf16.h>
#include <math.h>

#define BATCH 64
#define HW 28
#define PIX 784           // 28*28
#define LATENT 256
#define LABEL 10
#define FEAT 50176        // 64*28*28
#define KS 7
#define KCH 7168          // 50176/7

__device__ __forceinline__ float sgnf(float v) {
    return (v > 0.f) ? 1.f : ((v < 0.f) ? -1.f : 0.f);
}

// ---------------------------------------------------------------------------
// 5x5 pad-2 conv, register-blocked. Serves conv-transpose via FLIP template.
// grid = (B, OC/G), block = 256. in: [B][IC][28][28], out: [B][OC][28][28]
// ---------------------------------------------------------------------------
template<int G, int FLIP>
__global__ __launch_bounds__(256) void conv5_k(const float* __restrict__ in,
                        const float* __restrict__ w,
                        const float* __restrict__ bias, float* __restrict__ out,
                        int IC, int OC, int relu) {
    int b = blockIdx.x, oc0 = blockIdx.y * G;
    __shared__ float plp[32][32];   // 4 KB padded tile
    int tid = threadIdx.x;

    // zero the tile once (borders persist across ic iterations)
    *(float4*)&((float*)plp)[tid * 4] = make_float4(0.f, 0.f, 0.f, 0.f);

    bool act = tid < 196;
    int y = tid / 7, q = tid % 7, x0 = q * 4;

    float acc[G][4];
    #pragma unroll
    for (int g = 0; g < G; ++g)
        #pragma unroll
        for (int xi = 0; xi < 4; ++xi) acc[g][xi] = 0.f;

    for (int ic = 0; ic < IC; ++ic) {
        __syncthreads();
        if (act) {
            float4 v = *(const float4*)&in[((size_t)(b * IC + ic)) * PIX + tid * 4];
            *(float2*)&plp[y + 2][4 * q + 2] = make_float2(v.x, v.y);
            *(float2*)&plp[y + 2][4 * q + 4] = make_float2(v.z, v.w);
        }
        __syncthreads();
        if (act) {
            #pragma unroll
            for (int dy = 0; dy < 5; ++dy) {
                float4 ra = *(float4*)&plp[y + dy][x0];
                float4 rb = *(float4*)&plp[y + dy][x0 + 4];
                float rw[8] = {ra.x, ra.y, ra.z, ra.w, rb.x, rb.y, rb.z, rb.w};
                #pragma unroll
                for (int g = 0; g < G; ++g) {
                    #pragma unroll
                    for (int dx = 0; dx < 5; ++dx) {
                        float wv = FLIP
                            ? w[((size_t)ic * OC + (oc0 + g)) * 25 + (4 - dy) * 5 + (4 - dx)]
                            : w[((size_t)(oc0 + g) * IC + ic) * 25 + dy * 5 + dx];
                        #pragma unroll
                        for (int xi = 0; xi < 4; ++xi)
                            acc[g][xi] += rw[xi + dx] * wv;
                    }
                }
            }
        }
    }
    if (act) {
        #pragma unroll
        for (int g = 0; g < G; ++g) {
            float bv = bias[oc0 + g];
            float4 o;
            o.x = acc[g][0] + bv;
            o.y = acc[g][1] + bv;
            o.z = acc[g][2] + bv;
            o.w = acc[g][3] + bv;
            if (relu) {
                o.x = fmaxf(o.x, 0.f); o.y = fmaxf(o.y, 0.f);
                o.z = fmaxf(o.z, 0.f); o.w = fmaxf(o.w, 0.f);
            }
            *(float4*)&out[((size_t)(b * OC + (oc0 + g))) * PIX + y * HW + x0] = o;
        }
    }
}

// ---------------------------------------------------------------------------
// Encoder FC partials: z_pre[m][n] = sum_k x[m][k] * w[n][k]
// ---------------------------------------------------------------------------
__global__ void enc_fc_part_k(const float* __restrict__ x, const float* __restrict__ w,
                              float* __restrict__ part) {
    int n0 = blockIdx.x * 4;
    int ks = blockIdx.y;
    int kl = threadIdx.x & 31;
    int mi = threadIdx.x >> 5;   // 0..7

    float acc[8][4];
    #pragma unroll
    for (int mg = 0; mg < 8; ++mg)
        #pragma unroll
        for (int nt = 0; nt < 4; ++nt) acc[mg][nt] = 0.f;

    int kend = (ks + 1) * KCH;
    for (int kk = ks * KCH + kl; kk < kend; kk += 32) {
        float xv[8];
        #pragma unroll
        for (int mg = 0; mg < 8; ++mg)
            xv[mg] = x[(mg * 8 + mi) * FEAT + kk];
        #pragma unroll
        for (int nt = 0; nt < 4; ++nt) {
            float wv = w[(n0 + nt) * FEAT + kk];
            #pragma unroll
            for (int mg = 0; mg < 8; ++mg) acc[mg][nt] += xv[mg] * wv;
        }
    }

    #pragma unroll
    for (int mg = 0; mg < 8; ++mg) {
        #pragma unroll
        for (int nt = 0; nt < 4; ++nt) {
            float v = acc[mg][nt];
            v += __shfl_xor(v, 16, 64);
            v += __shfl_xor(v, 8, 64);
            v += __shfl_xor(v, 4, 64);
            v += __shfl_xor(v, 2, 64);
            v += __shfl_xor(v, 1, 64);
            if (kl == 0)
                part[(ks * BATCH + (mg * 8 + mi)) * LATENT + (n0 + nt)] = v;
        }
    }
}

// grid 64 (m), block 256 (n): z = tanh(sum_ks part + b); also emit
// xsaT[n][m] = atanh(tanh(pre)) for the decoder (exact reference semantics,
// transposed layout for the decoder's lane=m access).
__global__ void enc_fc_fin_k(const float* __restrict__ part, const float* __restrict__ bias,
                             float* __restrict__ z, float* __restrict__ xsaT) {
    int m = blockIdx.x;
    int n = threadIdx.x;
    int idx = m * 256 + n;
    float a = bias[n];
    for (int ksi = 0; ksi < KS; ++ksi) a += part[ksi * BATCH * LATENT + idx];
    float zv = tanhf(a);
    z[idx] = zv;
    xsaT[n * BATCH + m] = atanhf(zv);
}

// ---------------------------------------------------------------------------
// Hopfield weight
// ---------------------------------------------------------------------------
__global__ void hop_rho_k(const float* __restrict__ ll, float* __restrict__ rho_out) {
    float p = 0.f;
    for (int t = threadIdx.x; t < LABEL * LATENT; t += 256) p += sgnf(ll[t]);
    __shared__ float red[8];
    for (int o = 32; o; o >>= 1) p += __shfl_down(p, o, 64);
    if ((threadIdx.x & 63) == 0) red[threadIdx.x >> 6] = p;
    __syncthreads();
    if (threadIdx.x == 0)
        rho_out[0] = (red[0] + red[1] + red[2] + red[3]) / (float)(LABEL * LATENT);
}

__global__ void hop_w_k(const float* __restrict__ ll, const float* __restrict__ rho_p,
                        float* __restrict__ wout) {
    int i = blockIdx.x, j = threadIdx.x;
    float rho = rho_p[0];
    float acc = 0.f;
    #pragma unroll
    for (int l = 0; l < LABEL; ++l) {
        float a = sgnf(ll[l * LATENT + i]) - rho;
        float b = sgnf(ll[l * LATENT + j]) - rho;
        acc += a * b;
    }
    wout[i * LATENT + j] = (i == j) ? 0.f : acc / 10.f;
}

// ---------------------------------------------------------------------------
// Cluster iteration + cluster softmax head.
// grid 64 (sample), block 1024 = 4 j-quarters x 256 i.
// ---------------------------------------------------------------------------
__global__ __launch_bounds__(1024) void cluster_k(const float* __restrict__ z,
                          const float* __restrict__ w,
                          const float* __restrict__ ll, float* __restrict__ out) {
    int b = blockIdx.x;
    int t = threadIdx.x;
    int i = t & 255;
    int q = t >> 8;           // 0..3 (j-quarter)
    int lane = t & 63;
    int wvid = t >> 6;        // wave 0..15

    __shared__ float s_sh[LATENT];
    __shared__ float part[1024];
    __shared__ float red[4];
    __shared__ float cflag[4];
    __shared__ int ctl_sh;
    __shared__ float logit[LABEL];

    float wreg[64];
    #pragma unroll
    for (int jj = 0; jj < 64; ++jj)
        wreg[jj] = w[(q * 64 + jj) * LATENT + i];

    float s_cur = 0.f, s_old = 2.f, v = 0.f;
    float e_prev = 0.f;       // live on thread 0 only
    if (q == 0) {
        s_cur = sgnf(z[b * LATENT + i]);
        s_sh[i] = s_cur;
    }
    __syncthreads();

    // prologue: v = w @ s0, e_prev = energy(s0)
    {
        float p0 = 0.f, p1 = 0.f;
        #pragma unroll
        for (int jj = 0; jj < 64; jj += 2) {
            p0 += wreg[jj]     * s_sh[q * 64 + jj];
            p1 += wreg[jj + 1] * s_sh[q * 64 + jj + 1];
        }
        part[t] = p0 + p1;
    }
    __syncthreads();
    if (q == 0) {
        v = part[i] + part[i + 256] + part[i + 512] + part[i + 768];
        float p = s_cur * v;
        #pragma unroll
        for (int o = 32; o; o >>= 1) p += __shfl_down(p, o, 64);
        if (lane == 0) red[wvid] = p;
    }
    __syncthreads();
    if (t == 0) e_prev = -(red[0] + red[1] + red[2] + red[3]);

    for (int it = 0; it < LATENT; ++it) {
        if (q == 0) {
            float ns = sgnf(v);                       // state_{it+1}
            unsigned long long m = __ballot(ns == s_old);  // vs state_{it-1}
            if (lane == 0) cflag[wvid] = (m == ~0ull) ? 1.f : 0.f;
            s_sh[i] = ns;
            s_old = s_cur;
            s_cur = ns;
        }
        __syncthreads();
        {
            float p0 = 0.f, p1 = 0.f;
            #pragma unroll
            for (int jj = 0; jj < 64; jj += 2) {
                p0 += wreg[jj]     * s_sh[q * 64 + jj];
                p1 += wreg[jj + 1] * s_sh[q * 64 + jj + 1];
            }
            part[t] = p0 + p1;
        }
        __syncthreads();
        if (q == 0) {
            v = part[i] + part[i + 256] + part[i + 512] + part[i + 768];
            float p = s_cur * v;                      // energy(new state) terms
            #pragma unroll
            for (int o = 32; o; o >>= 1) p += __shfl_down(p, o, 64);
            if (lane == 0) red[wvid] = p;
        }
        __syncthreads();
        if (t == 0) {
            float e = -(red[0] + red[1] + red[2] + red[3]);
            int c = 0;
            if (e == e_prev) c = 1;                   // reference done-fires: keep ns
            else if (it >= 1 && cflag[0] != 0.f && cflag[1] != 0.f &&
                     cflag[2] != 0.f && cflag[3] != 0.f)
                c = (((LATENT - 1 - it) & 1) == 0) ? 2 : 3;  // 2-cycle parity
            else e_prev = e;
            ctl_sh = c;
        }
        __syncthreads();
        int c = ctl_sh;
        if (c != 0) {
            if (c == 3 && q == 0) s_sh[i] = s_old;    // odd remaining: prior state
            break;
        }
    }
    __syncthreads();

    // logits: wave c (c<10) computes clustered . ll[c]
    if (wvid < LABEL) {
        float p = 0.f;
        #pragma unroll
        for (int r = 0; r < 4; ++r)
            p += s_sh[r * 64 + lane] * ll[wvid * LATENT + r * 64 + lane];
        #pragma unroll
        for (int o = 32; o; o >>= 1) p += __shfl_down(p, o, 64);
        if (lane == 0) logit[wvid] = p;
    }
    __syncthreads();
    if (t == 0) {
        float mx = logit[0];
        for (int c = 1; c < LABEL; ++c) mx = fmaxf(mx, logit[c]);
        float ex[LABEL];
        float s = 0.f;
        for (int c = 0; c < LABEL; ++c) { ex[c] = expf(logit[c] - mx); s += ex[c]; }
        for (int c = 0; c < LABEL; ++c) out[b * LABEL + c] = ex[c] / s;
    }
}

// class_probs = softmax(z @ sm_w^T + sm_b). grid 64, block 256.
__device__ __forceinline__ float block_sum256(float p, float* red) {
    __syncthreads();
    for (int o = 32; o; o >>= 1) p += __shfl_down(p, o, 64);
    if ((threadIdx.x & 63) == 0) red[threadIdx.x >> 6] = p;
    __syncthreads();
    return red[0] + red[1] + red[2] + red[3];
}

__global__ void class_k(const float* __restrict__ z, const float* __restrict__ smw,
                        const float* __restrict__ smb, float* __restrict__ out) {
    int b = blockIdx.x;
    int i = threadIdx.x;
    __shared__ float red[8];
    __shared__ float logit[LABEL];
    float zi = z[b * LATENT + i];
    for (int c = 0; c < LABEL; ++c) {
        float p = zi * smw[c * LATENT + i];
        float t = block_sum256(p, red);
        if (i == 0) logit[c] = t + smb[c];
    }
    __syncthreads();
    if (i == 0) {
        float mx = logit[0];
        for (int c = 1; c < LABEL; ++c) mx = fmaxf(mx, logit[c]);
        float ex[LABEL];
        float s = 0.f;
        for (int c = 0; c < LABEL; ++c) { ex[c] = expf(logit[c] - mx); s += ex[c]; }
        for (int c = 0; c < LABEL; ++c) out[b * LABEL + c] = ex[c] / s;
    }
}

// ---------------------------------------------------------------------------
// Decoder FC: y[m][n] = xsaT^T @ w^T + b.  m = lane (64), 16 n per wave.
// grid 784 (n-chunks of 64), block 256 = 4 waves.
// xsaT: [LATENT][BATCH] (atanh values, transposed). Staged to 64 KB LDS.
// Weight loads are wave-uniform broadcast float4 (one 64B line each, every
// element fetched exactly once chip-wide). Writes: 4x float4 per lane,
// consecutive n -> line-combined.
// ---------------------------------------------------------------------------
__global__ __launch_bounds__(256) void dec_fc_k(const float* __restrict__ xsa,
                         const float* __restrict__ w,
                         const float* __restrict__ bias, float* __restrict__ y) {
    __shared__ float xsT[LATENT * BATCH];   // 64 KB
    int tid = threadIdx.x;
    #pragma unroll
    for (int i = 0; i < 16; ++i)
        *(float4*)&xsT[i * 1024 + tid * 4] = *(const float4*)&xsa[i * 1024 + tid * 4];
    __syncthreads();

    int lane = tid & 63;        // m
    int wv = tid >> 6;          // 0..3
    int nbase = blockIdx.x * 64 + wv * 16;

    float acc[16];
    #pragma unroll
    for (int nt = 0; nt < 16; ++nt) acc[nt] = 0.f;

    for (int kq = 0; kq < 64; ++kq) {
        int k0 = kq * 4;
        float xv0 = xsT[(k0 + 0) * BATCH + lane];
        float xv1 = xsT[(k0 + 1) * BATCH + lane];
        float xv2 = xsT[(k0 + 2) * BATCH + lane];
        float xv3 = xsT[(k0 + 3) * BATCH + lane];
        #pragma unroll
        for (int nt = 0; nt < 16; ++nt) {
            float4 wv4 = *(const float4*)&w[(size_t)(nbase + nt) * LATENT + k0];
            acc[nt] += xv0 * wv4.x + xv1 * wv4.y + xv2 * wv4.z + xv3 * wv4.w;
        }
    }

    #pragma unroll
    for (int nq = 0; nq < 4; ++nq) {
        float4 o;
        o.x = acc[nq * 4 + 0] + bias[nbase + nq * 4 + 0];
        o.y = acc[nq * 4 + 1] + bias[nbase + nq * 4 + 1];
        o.z = acc[nq * 4 + 2] + bias[nbase + nq * 4 + 2];
        o.w = acc[nq * 4 + 3] + bias[nbase + nq * 4 + 3];
        *(float4*)&y[(size_t)lane * FEAT + nbase + nq * 4] = o;
    }
}

// ---------------------------------------------------------------------------
extern "C" void kernel_launch(void* const* d_in, const int* in_sizes, int n_in,
                              void* d_out, int out_size, void* d_ws, size_t ws_size,
                              hipStream_t stream) {
    const float* images   = (const float*)d_in[0];
    const float* c1w      = (const float*)d_in[1];
    const float* c1b      = (const float*)d_in[2];
    const float* c2w      = (const float*)d_in[3];
    const float* c2b      = (const float*)d_in[4];
    const float* efw      = (const float*)d_in[5];
    const float* efb      = (const float*)d_in[6];
    const float* dfw      = (const float*)d_in[7];
    const float* dfb      = (const float*)d_in[8];
    const float* ct2w     = (const float*)d_in[9];
    const float* ct2b     = (const float*)d_in[10];
    const float* ct1w     = (const float*)d_in[11];
    const float* ct1b     = (const float*)d_in[12];
    const float* smw      = (const float*)d_in[13];
    const float* smb      = (const float*)d_in[14];
    const float* ll       = (const float*)d_in[15];

    float* out = (float*)d_out;
    float* ws  = (float*)d_ws;

    // ws layout (floats)
    float* big0 = ws;                                  // 64*64*784 = 3211264 (a2, later y)
    float* big1 = ws + 3211264;                        // 64*32*784 = 1605632 (a1, later ct2 out)
    float* part = ws + 3211264 + 1605632;              // 7*64*256 = 114688
    float* z    = part + KS * BATCH * LATENT;          // 16384
    float* whop = z + BATCH * LATENT;                  // 65536
    float* rho  = whop + LATENT * LATENT;              // 1
    float* xsa  = rho + 4;                             // 256*64 = 16384

    // encoder
    conv5_k<4,0><<<dim3(BATCH, 8), 256, 0, stream>>>(images, c1w, c1b, big1, 1, 32, 1);
    conv5_k<4,0><<<dim3(BATCH, 16), 256, 0, stream>>>(big1, c2w, c2b, big0, 32, 64, 1);
    enc_fc_part_k<<<dim3(64, KS), 256, 0, stream>>>(big0, efw, part);
    enc_fc_fin_k<<<BATCH, 256, 0, stream>>>(part, efb, z, xsa);

    // hopfield
    hop_rho_k<<<1, 256, 0, stream>>>(ll, rho);
    hop_w_k<<<LATENT, 256, 0, stream>>>(ll, rho, whop);
    cluster_k<<<BATCH, 1024, 0, stream>>>(z, whop, ll, out);           // cluster_probs
    class_k<<<BATCH, 256, 0, stream>>>(z, smw, smb, out + 640);        // class_probs

    // decoder
    dec_fc_k<<<FEAT / 64, 256, 0, stream>>>(xsa, dfw, dfb, big0);
    conv5_k<4,1><<<dim3(BATCH, 8), 256, 0, stream>>>(big0, ct2w, ct2b, big1, 64, 32, 1);
    conv5_k<1,1><<<dim3(BATCH, 1), 256, 0, stream>>>(big1, ct1w, ct1b, out + 1280, 32, 1, 0);
}

// Round 5
// 452.641 us; speedup vs baseline: 5.0515x; 1.1643x over previous
//
#include <hip/hip_runtime.h>
#include <hip/hip_bf16.h>
#include <math.h>

#define BATCH 64
#define HW 28
#define PIX 784           // 28*28
#define LATENT 256
#define LABEL 10
#define FEAT 50176        // 64*28*28
#define KS 7
#define KCH 7168          // 50176/7
#define TSTR 36           // padded LDS tile row stride (floats)

__device__ __forceinline__ float sgnf(float v) {
    return (v > 0.f) ? 1.f : ((v < 0.f) ? -1.f : 0.f);
}

// ---------------------------------------------------------------------------
// 5x5 pad-2 conv, register-blocked. Serves conv-transpose via FLIP template.
// grid = (B, OC/G), block = 256. in: [B][IC][28][28], out: [B][OC][28][28]
// Compute mapping: q = tid&7 (x-strip of 4), y = tid>>3  -> every 8-lane LDS
// window hits 8 distinct bank groups (conflict-free b128 reads). Row stride
// 36 keeps float4 alignment and decorrelates rows across larger windows.
// Double-buffered tile, one barrier per ic; next-ic global load issued before
// compute so its latency hides under the FMAs.
// ---------------------------------------------------------------------------
template<int G, int FLIP>
__global__ __launch_bounds__(256) void conv5_k(const float* __restrict__ in,
                        const float* __restrict__ w,
                        const float* __restrict__ bias, float* __restrict__ out,
                        int IC, int OC, int relu) {
    int b = blockIdx.x, oc0 = blockIdx.y * G;
    __shared__ float plp[2][32 * TSTR];   // 2 x 4.5 KB padded tiles
    int tid = threadIdx.x;

    // zero both buffers (borders persist; interiors rewritten each ic)
    for (int t = tid; t < 2 * 32 * TSTR; t += 256) ((float*)plp)[t] = 0.f;

    // staging mapping (196 threads, strip-of-4, 7 strips/row)
    bool actS = tid < 196;
    int ys = tid / 7, qs = tid % 7;

    // compute mapping (8-wide strips: q 0..6 active, y 0..27)
    int q = tid & 7, yy = tid >> 3;
    bool actC = (q < 7) && (yy < 28);
    int x0 = q * 4;

    float acc[G][4];
    #pragma unroll
    for (int g = 0; g < G; ++g)
        #pragma unroll
        for (int xi = 0; xi < 4; ++xi) acc[g][xi] = 0.f;

    __syncthreads();
    // preload ic = 0
    if (actS) {
        float4 v = *(const float4*)&in[((size_t)(b * IC + 0)) * PIX + tid * 4];
        *(float2*)&plp[0][(ys + 2) * TSTR + 4 * qs + 2] = make_float2(v.x, v.y);
        *(float2*)&plp[0][(ys + 2) * TSTR + 4 * qs + 4] = make_float2(v.z, v.w);
    }
    __syncthreads();

    for (int ic = 0; ic < IC; ++ic) {
        float4 vn;
        bool more = (ic + 1) < IC;
        if (more && actS)
            vn = *(const float4*)&in[((size_t)(b * IC + ic + 1)) * PIX + tid * 4];

        const float* tile = plp[ic & 1];
        if (actC) {
            #pragma unroll
            for (int dy = 0; dy < 5; ++dy) {
                float4 ra = *(const float4*)&tile[(yy + dy) * TSTR + x0];
                float4 rb = *(const float4*)&tile[(yy + dy) * TSTR + x0 + 4];
                float rw[8] = {ra.x, ra.y, ra.z, ra.w, rb.x, rb.y, rb.z, rb.w};
                #pragma unroll
                for (int g = 0; g < G; ++g) {
                    #pragma unroll
                    for (int dx = 0; dx < 5; ++dx) {
                        float wv = FLIP
                            ? w[((size_t)ic * OC + (oc0 + g)) * 25 + (4 - dy) * 5 + (4 - dx)]
                            : w[((size_t)(oc0 + g) * IC + ic) * 25 + dy * 5 + dx];
                        #pragma unroll
                        for (int xi = 0; xi < 4; ++xi)
                            acc[g][xi] += rw[xi + dx] * wv;
                    }
                }
            }
        }
        if (more && actS) {
            float* nt = plp[(ic + 1) & 1];
            *(float2*)&nt[(ys + 2) * TSTR + 4 * qs + 2] = make_float2(vn.x, vn.y);
            *(float2*)&nt[(ys + 2) * TSTR + 4 * qs + 4] = make_float2(vn.z, vn.w);
        }
        __syncthreads();
    }

    if (actC) {
        #pragma unroll
        for (int g = 0; g < G; ++g) {
            float bv = bias[oc0 + g];
            float4 o;
            o.x = acc[g][0] + bv;
            o.y = acc[g][1] + bv;
            o.z = acc[g][2] + bv;
            o.w = acc[g][3] + bv;
            if (relu) {
                o.x = fmaxf(o.x, 0.f); o.y = fmaxf(o.y, 0.f);
                o.z = fmaxf(o.z, 0.f); o.w = fmaxf(o.w, 0.f);
            }
            *(float4*)&out[((size_t)(b * OC + (oc0 + g))) * PIX + yy * HW + x0] = o;
        }
    }
}

// ---------------------------------------------------------------------------
// Encoder FC partials: z_pre[m][n] = sum_k x[m][k] * w[n][k]
// grid = (64 n-groups of 4, 7 k-chunks), block 256 = 32 k-lanes x 8 m.
// float4 k-vectorized: lane kl covers k in [4kl, 4kl+4) mod 128.
// ---------------------------------------------------------------------------
__global__ void enc_fc_part_k(const float* __restrict__ x, const float* __restrict__ w,
                              float* __restrict__ part) {
    int n0 = blockIdx.x * 4;
    int ks = blockIdx.y;
    int kl = threadIdx.x & 31;
    int mi = threadIdx.x >> 5;   // 0..7

    float acc[8][4];
    #pragma unroll
    for (int mg = 0; mg < 8; ++mg)
        #pragma unroll
        for (int nt = 0; nt < 4; ++nt) acc[mg][nt] = 0.f;

    int kend = (ks + 1) * KCH;
    for (int kk = ks * KCH + kl * 4; kk < kend; kk += 128) {
        float4 xv[8];
        #pragma unroll
        for (int mg = 0; mg < 8; ++mg)
            xv[mg] = *(const float4*)&x[(size_t)(mg * 8 + mi) * FEAT + kk];
        #pragma unroll
        for (int nt = 0; nt < 4; ++nt) {
            float4 wv = *(const float4*)&w[(size_t)(n0 + nt) * FEAT + kk];
            #pragma unroll
            for (int mg = 0; mg < 8; ++mg) {
                acc[mg][nt] += xv[mg].x * wv.x + xv[mg].y * wv.y
                             + xv[mg].z * wv.z + xv[mg].w * wv.w;
            }
        }
    }

    #pragma unroll
    for (int mg = 0; mg < 8; ++mg) {
        #pragma unroll
        for (int nt = 0; nt < 4; ++nt) {
            float v = acc[mg][nt];
            v += __shfl_xor(v, 16, 64);
            v += __shfl_xor(v, 8, 64);
            v += __shfl_xor(v, 4, 64);
            v += __shfl_xor(v, 2, 64);
            v += __shfl_xor(v, 1, 64);
            if (kl == 0)
                part[(ks * BATCH + (mg * 8 + mi)) * LATENT + (n0 + nt)] = v;
        }
    }
}

// grid 64 (m), block 256 (n): z = tanh(sum_ks part + b); also emit
// xsaT[n][m] = atanh(tanh(pre)) for the decoder.
__global__ void enc_fc_fin_k(const float* __restrict__ part, const float* __restrict__ bias,
                             float* __restrict__ z, float* __restrict__ xsaT) {
    int m = blockIdx.x;
    int n = threadIdx.x;
    int idx = m * 256 + n;
    float a = bias[n];
    for (int ksi = 0; ksi < KS; ++ksi) a += part[ksi * BATCH * LATENT + idx];
    float zv = tanhf(a);
    z[idx] = zv;
    xsaT[n * BATCH + m] = atanhf(zv);
}

// ---------------------------------------------------------------------------
// Hopfield weight
// ---------------------------------------------------------------------------
__global__ void hop_rho_k(const float* __restrict__ ll, float* __restrict__ rho_out) {
    float p = 0.f;
    for (int t = threadIdx.x; t < LABEL * LATENT; t += 256) p += sgnf(ll[t]);
    __shared__ float red[8];
    for (int o = 32; o; o >>= 1) p += __shfl_down(p, o, 64);
    if ((threadIdx.x & 63) == 0) red[threadIdx.x >> 6] = p;
    __syncthreads();
    if (threadIdx.x == 0)
        rho_out[0] = (red[0] + red[1] + red[2] + red[3]) / (float)(LABEL * LATENT);
}

__global__ void hop_w_k(const float* __restrict__ ll, const float* __restrict__ rho_p,
                        float* __restrict__ wout) {
    int i = blockIdx.x, j = threadIdx.x;
    float rho = rho_p[0];
    float acc = 0.f;
    #pragma unroll
    for (int l = 0; l < LABEL; ++l) {
        float a = sgnf(ll[l * LATENT + i]) - rho;
        float b = sgnf(ll[l * LATENT + j]) - rho;
        acc += a * b;
    }
    wout[i * LATENT + j] = (i == j) ? 0.f : acc / 10.f;
}

// ---------------------------------------------------------------------------
// Cluster iteration + cluster softmax head.
// grid 64 (sample), block 1024 = 4 j-quarters x 256 i.
// ---------------------------------------------------------------------------
__global__ __launch_bounds__(1024) void cluster_k(const float* __restrict__ z,
                          const float* __restrict__ w,
                          const float* __restrict__ ll, float* __restrict__ out) {
    int b = blockIdx.x;
    int t = threadIdx.x;
    int i = t & 255;
    int q = t >> 8;           // 0..3 (j-quarter)
    int lane = t & 63;
    int wvid = t >> 6;        // wave 0..15

    __shared__ float s_sh[LATENT];
    __shared__ float part[1024];
    __shared__ float red[4];
    __shared__ float cflag[4];
    __shared__ int ctl_sh;
    __shared__ float logit[LABEL];

    float wreg[64];
    #pragma unroll
    for (int jj = 0; jj < 64; ++jj)
        wreg[jj] = w[(q * 64 + jj) * LATENT + i];

    float s_cur = 0.f, s_old = 2.f, v = 0.f;
    float e_prev = 0.f;       // live on thread 0 only
    if (q == 0) {
        s_cur = sgnf(z[b * LATENT + i]);
        s_sh[i] = s_cur;
    }
    __syncthreads();

    // prologue: v = w @ s0, e_prev = energy(s0)
    {
        float p0 = 0.f, p1 = 0.f;
        #pragma unroll
        for (int jj = 0; jj < 64; jj += 2) {
            p0 += wreg[jj]     * s_sh[q * 64 + jj];
            p1 += wreg[jj + 1] * s_sh[q * 64 + jj + 1];
        }
        part[t] = p0 + p1;
    }
    __syncthreads();
    if (q == 0) {
        v = part[i] + part[i + 256] + part[i + 512] + part[i + 768];
        float p = s_cur * v;
        #pragma unroll
        for (int o = 32; o; o >>= 1) p += __shfl_down(p, o, 64);
        if (lane == 0) red[wvid] = p;
    }
    __syncthreads();
    if (t == 0) e_prev = -(red[0] + red[1] + red[2] + red[3]);

    for (int it = 0; it < LATENT; ++it) {
        if (q == 0) {
            float ns = sgnf(v);                       // state_{it+1}
            unsigned long long m = __ballot(ns == s_old);  // vs state_{it-1}
            if (lane == 0) cflag[wvid] = (m == ~0ull) ? 1.f : 0.f;
            s_sh[i] = ns;
            s_old = s_cur;
            s_cur = ns;
        }
        __syncthreads();
        {
            float p0 = 0.f, p1 = 0.f;
            #pragma unroll
            for (int jj = 0; jj < 64; jj += 2) {
                p0 += wreg[jj]     * s_sh[q * 64 + jj];
                p1 += wreg[jj + 1] * s_sh[q * 64 + jj + 1];
            }
            part[t] = p0 + p1;
        }
        __syncthreads();
        if (q == 0) {
            v = part[i] + part[i + 256] + part[i + 512] + part[i + 768];
            float p = s_cur * v;                      // energy(new state) terms
            #pragma unroll
            for (int o = 32; o; o >>= 1) p += __shfl_down(p, o, 64);
            if (lane == 0) red[wvid] = p;
        }
        __syncthreads();
        if (t == 0) {
            float e = -(red[0] + red[1] + red[2] + red[3]);
            int c = 0;
            if (e == e_prev) c = 1;                   // reference done-fires: keep ns
            else if (it >= 1 && cflag[0] != 0.f && cflag[1] != 0.f &&
                     cflag[2] != 0.f && cflag[3] != 0.f)
                c = (((LATENT - 1 - it) & 1) == 0) ? 2 : 3;  // 2-cycle parity
            else e_prev = e;
            ctl_sh = c;
        }
        __syncthreads();
        int c = ctl_sh;
        if (c != 0) {
            if (c == 3 && q == 0) s_sh[i] = s_old;    // odd remaining: prior state
            break;
        }
    }
    __syncthreads();

    // logits: wave c (c<10) computes clustered . ll[c]
    if (wvid < LABEL) {
        float p = 0.f;
        #pragma unroll
        for (int r = 0; r < 4; ++r)
            p += s_sh[r * 64 + lane] * ll[wvid * LATENT + r * 64 + lane];
        #pragma unroll
        for (int o = 32; o; o >>= 1) p += __shfl_down(p, o, 64);
        if (lane == 0) logit[wvid] = p;
    }
    __syncthreads();
    if (t == 0) {
        float mx = logit[0];
        for (int c = 1; c < LABEL; ++c) mx = fmaxf(mx, logit[c]);
        float ex[LABEL];
        float s = 0.f;
        for (int c = 0; c < LABEL; ++c) { ex[c] = expf(logit[c] - mx); s += ex[c]; }
        for (int c = 0; c < LABEL; ++c) out[b * LABEL + c] = ex[c] / s;
    }
}

// class_probs = softmax(z @ sm_w^T + sm_b). grid 64, block 256.
__device__ __forceinline__ float block_sum256(float p, float* red) {
    __syncthreads();
    for (int o = 32; o; o >>= 1) p += __shfl_down(p, o, 64);
    if ((threadIdx.x & 63) == 0) red[threadIdx.x >> 6] = p;
    __syncthreads();
    return red[0] + red[1] + red[2] + red[3];
}

__global__ void class_k(const float* __restrict__ z, const float* __restrict__ smw,
                        const float* __restrict__ smb, float* __restrict__ out) {
    int b = blockIdx.x;
    int i = threadIdx.x;
    __shared__ float red[8];
    __shared__ float logit[LABEL];
    float zi = z[b * LATENT + i];
    for (int c = 0; c < LABEL; ++c) {
        float p = zi * smw[c * LATENT + i];
        float t = block_sum256(p, red);
        if (i == 0) logit[c] = t + smb[c];
    }
    __syncthreads();
    if (i == 0) {
        float mx = logit[0];
        for (int c = 1; c < LABEL; ++c) mx = fmaxf(mx, logit[c]);
        float ex[LABEL];
        float s = 0.f;
        for (int c = 0; c < LABEL; ++c) { ex[c] = expf(logit[c] - mx); s += ex[c]; }
        for (int c = 0; c < LABEL; ++c) out[b * LABEL + c] = ex[c] / s;
    }
}

// ---------------------------------------------------------------------------
// Decoder FC: y[m][n] = xsaT^T @ w^T + b.  m = lane (64), 16 n per wave.
// grid 784 (n-chunks of 64), block 256 = 4 waves.
// ---------------------------------------------------------------------------
__global__ __launch_bounds__(256) void dec_fc_k(const float* __restrict__ xsa,
                         const float* __restrict__ w,
                         const float* __restrict__ bias, float* __restrict__ y) {
    __shared__ float xsT[LATENT * BATCH];   // 64 KB
    int tid = threadIdx.x;
    #pragma unroll
    for (int i = 0; i < 16; ++i)
        *(float4*)&xsT[i * 1024 + tid * 4] = *(const float4*)&xsa[i * 1024 + tid * 4];
    __syncthreads();

    int lane = tid & 63;        // m
    int wv = tid >> 6;          // 0..3
    int nbase = blockIdx.x * 64 + wv * 16;

    float acc[16];
    #pragma unroll
    for (int nt = 0; nt < 16; ++nt) acc[nt] = 0.f;

    for (int kq = 0; kq < 64; ++kq) {
        int k0 = kq * 4;
        float xv0 = xsT[(k0 + 0) * BATCH + lane];
        float xv1 = xsT[(k0 + 1) * BATCH + lane];
        float xv2 = xsT[(k0 + 2) * BATCH + lane];
        float xv3 = xsT[(k0 + 3) * BATCH + lane];
        #pragma unroll
        for (int nt = 0; nt < 16; ++nt) {
            float4 wv4 = *(const float4*)&w[(size_t)(nbase + nt) * LATENT + k0];
            acc[nt] += xv0 * wv4.x + xv1 * wv4.y + xv2 * wv4.z + xv3 * wv4.w;
        }
    }

    #pragma unroll
    for (int nq = 0; nq < 4; ++nq) {
        float4 o;
        o.x = acc[nq * 4 + 0] + bias[nbase + nq * 4 + 0];
        o.y = acc[nq * 4 + 1] + bias[nbase + nq * 4 + 1];
        o.z = acc[nq * 4 + 2] + bias[nbase + nq * 4 + 2];
        o.w = acc[nq * 4 + 3] + bias[nbase + nq * 4 + 3];
        *(float4*)&y[(size_t)lane * FEAT + nbase + nq * 4] = o;
    }
}

// ---------------------------------------------------------------------------
extern "C" void kernel_launch(void* const* d_in, const int* in_sizes, int n_in,
                              void* d_out, int out_size, void* d_ws, size_t ws_size,
                              hipStream_t stream) {
    const float* images   = (const float*)d_in[0];
    const float* c1w      = (const float*)d_in[1];
    const float* c1b      = (const float*)d_in[2];
    const float* c2w      = (const float*)d_in[3];
    const float* c2b      = (const float*)d_in[4];
    const float* efw      = (const float*)d_in[5];
    const float* efb      = (const float*)d_in[6];
    const float* dfw      = (const float*)d_in[7];
    const float* dfb      = (const float*)d_in[8];
    const float* ct2w     = (const float*)d_in[9];
    const float* ct2b     = (const float*)d_in[10];
    const float* ct1w     = (const float*)d_in[11];
    const float* ct1b     = (const float*)d_in[12];
    const float* smw      = (const float*)d_in[13];
    const float* smb      = (const float*)d_in[14];
    const float* ll       = (const float*)d_in[15];

    float* out = (float*)d_out;
    float* ws  = (float*)d_ws;

    // ws layout (floats)
    float* big0 = ws;                                  // 64*64*784 = 3211264 (a2, later y)
    float* big1 = ws + 3211264;                        // 64*32*784 = 1605632 (a1, later ct2 out)
    float* part = ws + 3211264 + 1605632;              // 7*64*256 = 114688
    float* z    = part + KS * BATCH * LATENT;          // 16384
    float* whop = z + BATCH * LATENT;                  // 65536
    float* rho  = whop + LATENT * LATENT;              // 1
    float* xsa  = rho + 4;                             // 256*64 = 16384

    // encoder
    conv5_k<4,0><<<dim3(BATCH, 8), 256, 0, stream>>>(images, c1w, c1b, big1, 1, 32, 1);
    conv5_k<4,0><<<dim3(BATCH, 16), 256, 0, stream>>>(big1, c2w, c2b, big0, 32, 64, 1);
    enc_fc_part_k<<<dim3(64, KS), 256, 0, stream>>>(big0, efw, part);
    enc_fc_fin_k<<<BATCH, 256, 0, stream>>>(part, efb, z, xsa);

    // hopfield
    hop_rho_k<<<1, 256, 0, stream>>>(ll, rho);
    hop_w_k<<<LATENT, 256, 0, stream>>>(ll, rho, whop);
    cluster_k<<<BATCH, 1024, 0, stream>>>(z, whop, ll, out);           // cluster_probs
    class_k<<<BATCH, 256, 0, stream>>>(z, smw, smb, out + 640);        // class_probs

    // decoder
    dec_fc_k<<<FEAT / 64, 256, 0, stream>>>(xsa, dfw, dfb, big0);
    conv5_k<4,1><<<dim3(BATCH, 8), 256, 0, stream>>>(big0, ct2w, ct2b, big1, 64, 32, 1);
    conv5_k<1,1><<<dim3(BATCH, 1), 256, 0, stream>>>(big1, ct1w, ct1b, out + 1280, 32, 1, 0);
}

// Round 6
// 405.687 us; speedup vs baseline: 5.6362x; 1.1157x over previous
//
#include <hip/hip_runtime.h>
#include <hip/hip_bf16.h>
#include <math.h>

#define BATCH 64
#define HW 28
#define PIX 784           // 28*28
#define LATENT 256
#define LABEL 10
#define FEAT 50176        // 64*28*28
#define KS 7
#define KCH 7168          // 50176/7
#define TSTR 36           // padded LDS tile row stride (floats)

__device__ __forceinline__ float sgnf(float v) {
    return (v > 0.f) ? 1.f : ((v < 0.f) ? -1.f : 0.f);
}

// ---------------------------------------------------------------------------
// 5x5 pad-2 conv, register-blocked. Serves conv-transpose via FLIP template.
// grid = (B, OC/G), block = 256. in: [B][IC][28][28], out: [B][OC][28][28]
// ---------------------------------------------------------------------------
template<int G, int FLIP>
__global__ __launch_bounds__(256) void conv5_k(const float* __restrict__ in,
                        const float* __restrict__ w,
                        const float* __restrict__ bias, float* __restrict__ out,
                        int IC, int OC, int relu) {
    int b = blockIdx.x, oc0 = blockIdx.y * G;
    __shared__ float plp[2][32 * TSTR];   // 2 x 4.5 KB padded tiles
    int tid = threadIdx.x;

    // zero both buffers (borders persist; interiors rewritten each ic)
    for (int t = tid; t < 2 * 32 * TSTR; t += 256) ((float*)plp)[t] = 0.f;

    // staging mapping (196 threads, strip-of-4, 7 strips/row)
    bool actS = tid < 196;
    int ys = tid / 7, qs = tid % 7;

    // compute mapping (8-wide strips: q 0..6 active, y 0..27)
    int q = tid & 7, yy = tid >> 3;
    bool actC = (q < 7) && (yy < 28);
    int x0 = q * 4;

    float acc[G][4];
    #pragma unroll
    for (int g = 0; g < G; ++g)
        #pragma unroll
        for (int xi = 0; xi < 4; ++xi) acc[g][xi] = 0.f;

    __syncthreads();
    // preload ic = 0
    if (actS) {
        float4 v = *(const float4*)&in[((size_t)(b * IC + 0)) * PIX + tid * 4];
        *(float2*)&plp[0][(ys + 2) * TSTR + 4 * qs + 2] = make_float2(v.x, v.y);
        *(float2*)&plp[0][(ys + 2) * TSTR + 4 * qs + 4] = make_float2(v.z, v.w);
    }
    __syncthreads();

    for (int ic = 0; ic < IC; ++ic) {
        float4 vn;
        bool more = (ic + 1) < IC;
        if (more && actS)
            vn = *(const float4*)&in[((size_t)(b * IC + ic + 1)) * PIX + tid * 4];

        const float* tile = plp[ic & 1];
        if (actC) {
            #pragma unroll
            for (int dy = 0; dy < 5; ++dy) {
                float4 ra = *(const float4*)&tile[(yy + dy) * TSTR + x0];
                float4 rb = *(const float4*)&tile[(yy + dy) * TSTR + x0 + 4];
                float rw[8] = {ra.x, ra.y, ra.z, ra.w, rb.x, rb.y, rb.z, rb.w};
                #pragma unroll
                for (int g = 0; g < G; ++g) {
                    #pragma unroll
                    for (int dx = 0; dx < 5; ++dx) {
                        float wv = FLIP
                            ? w[((size_t)ic * OC + (oc0 + g)) * 25 + (4 - dy) * 5 + (4 - dx)]
                            : w[((size_t)(oc0 + g) * IC + ic) * 25 + dy * 5 + dx];
                        #pragma unroll
                        for (int xi = 0; xi < 4; ++xi)
                            acc[g][xi] += rw[xi + dx] * wv;
                    }
                }
            }
        }
        if (more && actS) {
            float* nt = plp[(ic + 1) & 1];
            *(float2*)&nt[(ys + 2) * TSTR + 4 * qs + 2] = make_float2(vn.x, vn.y);
            *(float2*)&nt[(ys + 2) * TSTR + 4 * qs + 4] = make_float2(vn.z, vn.w);
        }
        __syncthreads();
    }

    if (actC) {
        #pragma unroll
        for (int g = 0; g < G; ++g) {
            float bv = bias[oc0 + g];
            float4 o;
            o.x = acc[g][0] + bv;
            o.y = acc[g][1] + bv;
            o.z = acc[g][2] + bv;
            o.w = acc[g][3] + bv;
            if (relu) {
                o.x = fmaxf(o.x, 0.f); o.y = fmaxf(o.y, 0.f);
                o.z = fmaxf(o.z, 0.f); o.w = fmaxf(o.w, 0.f);
            }
            *(float4*)&out[((size_t)(b * OC + (oc0 + g))) * PIX + yy * HW + x0] = o;
        }
    }
}

// ---------------------------------------------------------------------------
// Encoder FC partials: z_pre[m][n] = sum_k x[m][k] * w[n][k]
// grid = (64 n-groups of 4, 7 k-chunks), block 256 = 32 k-lanes x 8 m.
// ---------------------------------------------------------------------------
__global__ void enc_fc_part_k(const float* __restrict__ x, const float* __restrict__ w,
                              float* __restrict__ part) {
    int n0 = blockIdx.x * 4;
    int ks = blockIdx.y;
    int kl = threadIdx.x & 31;
    int mi = threadIdx.x >> 5;   // 0..7

    float acc[8][4];
    #pragma unroll
    for (int mg = 0; mg < 8; ++mg)
        #pragma unroll
        for (int nt = 0; nt < 4; ++nt) acc[mg][nt] = 0.f;

    int kend = (ks + 1) * KCH;
    for (int kk = ks * KCH + kl * 4; kk < kend; kk += 128) {
        float4 xv[8];
        #pragma unroll
        for (int mg = 0; mg < 8; ++mg)
            xv[mg] = *(const float4*)&x[(size_t)(mg * 8 + mi) * FEAT + kk];
        #pragma unroll
        for (int nt = 0; nt < 4; ++nt) {
            float4 wv = *(const float4*)&w[(size_t)(n0 + nt) * FEAT + kk];
            #pragma unroll
            for (int mg = 0; mg < 8; ++mg) {
                acc[mg][nt] += xv[mg].x * wv.x + xv[mg].y * wv.y
                             + xv[mg].z * wv.z + xv[mg].w * wv.w;
            }
        }
    }

    #pragma unroll
    for (int mg = 0; mg < 8; ++mg) {
        #pragma unroll
        for (int nt = 0; nt < 4; ++nt) {
            float v = acc[mg][nt];
            v += __shfl_xor(v, 16, 64);
            v += __shfl_xor(v, 8, 64);
            v += __shfl_xor(v, 4, 64);
            v += __shfl_xor(v, 2, 64);
            v += __shfl_xor(v, 1, 64);
            if (kl == 0)
                part[(ks * BATCH + (mg * 8 + mi)) * LATENT + (n0 + nt)] = v;
        }
    }
}

// grid 64 (m), block 256 (n): z = tanh(sum_ks part + b); also emit
// xsaT[n][m] = atanh(tanh(pre)) for the decoder.
__global__ void enc_fc_fin_k(const float* __restrict__ part, const float* __restrict__ bias,
                             float* __restrict__ z, float* __restrict__ xsaT) {
    int m = blockIdx.x;
    int n = threadIdx.x;
    int idx = m * 256 + n;
    float a = bias[n];
    for (int ksi = 0; ksi < KS; ++ksi) a += part[ksi * BATCH * LATENT + idx];
    float zv = tanhf(a);
    z[idx] = zv;
    xsaT[n * BATCH + m] = atanhf(zv);
}

// ---------------------------------------------------------------------------
// Hopfield weight
// ---------------------------------------------------------------------------
__global__ void hop_rho_k(const float* __restrict__ ll, float* __restrict__ rho_out) {
    float p = 0.f;
    for (int t = threadIdx.x; t < LABEL * LATENT; t += 256) p += sgnf(ll[t]);
    __shared__ float red[8];
    for (int o = 32; o; o >>= 1) p += __shfl_down(p, o, 64);
    if ((threadIdx.x & 63) == 0) red[threadIdx.x >> 6] = p;
    __syncthreads();
    if (threadIdx.x == 0)
        rho_out[0] = (red[0] + red[1] + red[2] + red[3]) / (float)(LABEL * LATENT);
}

__global__ void hop_w_k(const float* __restrict__ ll, const float* __restrict__ rho_p,
                        float* __restrict__ wout) {
    int i = blockIdx.x, j = threadIdx.x;
    float rho = rho_p[0];
    float acc = 0.f;
    #pragma unroll
    for (int l = 0; l < LABEL; ++l) {
        float a = sgnf(ll[l * LATENT + i]) - rho;
        float b = sgnf(ll[l * LATENT + j]) - rho;
        acc += a * b;
    }
    wout[i * LATENT + j] = (i == j) ? 0.f : acc / 10.f;
}

// ---------------------------------------------------------------------------
// Cluster iteration + cluster softmax head.
// grid 64 (sample), block 1024 = 4 j-quarters x 256 i.
// ---------------------------------------------------------------------------
__global__ __launch_bounds__(1024) void cluster_k(const float* __restrict__ z,
                          const float* __restrict__ w,
                          const float* __restrict__ ll, float* __restrict__ out) {
    int b = blockIdx.x;
    int t = threadIdx.x;
    int i = t & 255;
    int q = t >> 8;           // 0..3 (j-quarter)
    int lane = t & 63;
    int wvid = t >> 6;        // wave 0..15

    __shared__ float s_sh[LATENT];
    __shared__ float part[1024];
    __shared__ float red[4];
    __shared__ float cflag[4];
    __shared__ int ctl_sh;
    __shared__ float logit[LABEL];

    float wreg[64];
    #pragma unroll
    for (int jj = 0; jj < 64; ++jj)
        wreg[jj] = w[(q * 64 + jj) * LATENT + i];

    float s_cur = 0.f, s_old = 2.f, v = 0.f;
    float e_prev = 0.f;       // live on thread 0 only
    if (q == 0) {
        s_cur = sgnf(z[b * LATENT + i]);
        s_sh[i] = s_cur;
    }
    __syncthreads();

    // prologue: v = w @ s0, e_prev = energy(s0)
    {
        float p0 = 0.f, p1 = 0.f;
        #pragma unroll
        for (int jj = 0; jj < 64; jj += 2) {
            p0 += wreg[jj]     * s_sh[q * 64 + jj];
            p1 += wreg[jj + 1] * s_sh[q * 64 + jj + 1];
        }
        part[t] = p0 + p1;
    }
    __syncthreads();
    if (q == 0) {
        v = part[i] + part[i + 256] + part[i + 512] + part[i + 768];
        float p = s_cur * v;
        #pragma unroll
        for (int o = 32; o; o >>= 1) p += __shfl_down(p, o, 64);
        if (lane == 0) red[wvid] = p;
    }
    __syncthreads();
    if (t == 0) e_prev = -(red[0] + red[1] + red[2] + red[3]);

    for (int it = 0; it < LATENT; ++it) {
        if (q == 0) {
            float ns = sgnf(v);                       // state_{it+1}
            unsigned long long m = __ballot(ns == s_old);  // vs state_{it-1}
            if (lane == 0) cflag[wvid] = (m == ~0ull) ? 1.f : 0.f;
            s_sh[i] = ns;
            s_old = s_cur;
            s_cur = ns;
        }
        __syncthreads();
        {
            float p0 = 0.f, p1 = 0.f;
            #pragma unroll
            for (int jj = 0; jj < 64; jj += 2) {
                p0 += wreg[jj]     * s_sh[q * 64 + jj];
                p1 += wreg[jj + 1] * s_sh[q * 64 + jj + 1];
            }
            part[t] = p0 + p1;
        }
        __syncthreads();
        if (q == 0) {
            v = part[i] + part[i + 256] + part[i + 512] + part[i + 768];
            float p = s_cur * v;                      // energy(new state) terms
            #pragma unroll
            for (int o = 32; o; o >>= 1) p += __shfl_down(p, o, 64);
            if (lane == 0) red[wvid] = p;
        }
        __syncthreads();
        if (t == 0) {
            float e = -(red[0] + red[1] + red[2] + red[3]);
            int c = 0;
            if (e == e_prev) c = 1;                   // reference done-fires: keep ns
            else if (it >= 1 && cflag[0] != 0.f && cflag[1] != 0.f &&
                     cflag[2] != 0.f && cflag[3] != 0.f)
                c = (((LATENT - 1 - it) & 1) == 0) ? 2 : 3;  // 2-cycle parity
            else e_prev = e;
            ctl_sh = c;
        }
        __syncthreads();
        int c = ctl_sh;
        if (c != 0) {
            if (c == 3 && q == 0) s_sh[i] = s_old;    // odd remaining: prior state
            break;
        }
    }
    __syncthreads();

    // logits: wave c (c<10) computes clustered . ll[c]
    if (wvid < LABEL) {
        float p = 0.f;
        #pragma unroll
        for (int r = 0; r < 4; ++r)
            p += s_sh[r * 64 + lane] * ll[wvid * LATENT + r * 64 + lane];
        #pragma unroll
        for (int o = 32; o; o >>= 1) p += __shfl_down(p, o, 64);
        if (lane == 0) logit[wvid] = p;
    }
    __syncthreads();
    if (t == 0) {
        float mx = logit[0];
        for (int c = 1; c < LABEL; ++c) mx = fmaxf(mx, logit[c]);
        float ex[LABEL];
        float s = 0.f;
        for (int c = 0; c < LABEL; ++c) { ex[c] = expf(logit[c] - mx); s += ex[c]; }
        for (int c = 0; c < LABEL; ++c) out[b * LABEL + c] = ex[c] / s;
    }
}

// class_probs = softmax(z @ sm_w^T + sm_b). grid 64, block 256.
__device__ __forceinline__ float block_sum256(float p, float* red) {
    __syncthreads();
    for (int o = 32; o; o >>= 1) p += __shfl_down(p, o, 64);
    if ((threadIdx.x & 63) == 0) red[threadIdx.x >> 6] = p;
    __syncthreads();
    return red[0] + red[1] + red[2] + red[3];
}

__global__ void class_k(const float* __restrict__ z, const float* __restrict__ smw,
                        const float* __restrict__ smb, float* __restrict__ out) {
    int b = blockIdx.x;
    int i = threadIdx.x;
    __shared__ float red[8];
    __shared__ float logit[LABEL];
    float zi = z[b * LATENT + i];
    for (int c = 0; c < LABEL; ++c) {
        float p = zi * smw[c * LATENT + i];
        float t = block_sum256(p, red);
        if (i == 0) logit[c] = t + smb[c];
    }
    __syncthreads();
    if (i == 0) {
        float mx = logit[0];
        for (int c = 1; c < LABEL; ++c) mx = fmaxf(mx, logit[c]);
        float ex[LABEL];
        float s = 0.f;
        for (int c = 0; c < LABEL; ++c) { ex[c] = expf(logit[c] - mx); s += ex[c]; }
        for (int c = 0; c < LABEL; ++c) out[b * LABEL + c] = ex[c] / s;
    }
}

// ---------------------------------------------------------------------------
// Decoder FC v3: y[m][n] = xsaT^T @ w^T + b.  m = lane (64), 16 n per wave.
// grid 784 (n-chunks of 64), block 256 = 4 waves.
// Both operands staged in LDS via fully coalesced bulk loads, in two k-phases
// of 128 (xs 32KB + wt 32KB = 64KB -> 2 blocks/CU). Phase-1 global loads are
// issued BEFORE phase-0 compute (issue-early/write-late), so their latency
// hides under ~4000 cycles of FMAs. Weight reads in the k-loop are
// wave-uniform LDS broadcasts (~2 cyc) instead of global broadcast loads
// (~600-900 cyc) -> compute becomes VALU-bound.
// k-summation order identical to v2 (ascending k-quads).
// ---------------------------------------------------------------------------
__global__ __launch_bounds__(256) void dec_fc_k(const float* __restrict__ xsa,
                         const float* __restrict__ w,
                         const float* __restrict__ bias, float* __restrict__ y) {
    __shared__ float xs[128 * BATCH];   // 32 KB  [k_local][m]
    __shared__ float wt[64 * 128];      // 32 KB  [n_local][k_local]
    int tid = threadIdx.x;
    int lane = tid & 63;        // m
    int wv = tid >> 6;          // 0..3
    int n0 = blockIdx.x * 64;

    float acc[16];
    #pragma unroll
    for (int nt = 0; nt < 16; ++nt) acc[nt] = 0.f;

    float4 xr[8], wr[8];
    // stage phase 0 (k 0..127)
    #pragma unroll
    for (int i = 0; i < 8; ++i) {
        int j = i * 1024 + tid * 4;
        xr[i] = *(const float4*)&xsa[j];                       // xsaT linear copy
        int row = j >> 7, col = j & 127;
        wr[i] = *(const float4*)&w[(size_t)(n0 + row) * LATENT + col];
    }
    #pragma unroll
    for (int i = 0; i < 8; ++i) {
        int j = i * 1024 + tid * 4;
        *(float4*)&xs[j] = xr[i];
        *(float4*)&wt[j] = wr[i];
    }
    __syncthreads();

    // issue phase-1 global loads early (latency hides under phase-0 compute)
    #pragma unroll
    for (int i = 0; i < 8; ++i) {
        int j = i * 1024 + tid * 4;
        xr[i] = *(const float4*)&xsa[8192 + j];
        int row = j >> 7, col = j & 127;
        wr[i] = *(const float4*)&w[(size_t)(n0 + row) * LATENT + 128 + col];
    }

    // compute phase 0
    for (int kq = 0; kq < 32; ++kq) {
        int k0 = kq * 4;
        float xv0 = xs[(k0 + 0) * BATCH + lane];
        float xv1 = xs[(k0 + 1) * BATCH + lane];
        float xv2 = xs[(k0 + 2) * BATCH + lane];
        float xv3 = xs[(k0 + 3) * BATCH + lane];
        #pragma unroll
        for (int nt = 0; nt < 16; ++nt) {
            float4 wv4 = *(const float4*)&wt[(wv * 16 + nt) * 128 + k0];
            acc[nt] += xv0 * wv4.x + xv1 * wv4.y + xv2 * wv4.z + xv3 * wv4.w;
        }
    }
    __syncthreads();

    // write phase 1 to LDS
    #pragma unroll
    for (int i = 0; i < 8; ++i) {
        int j = i * 1024 + tid * 4;
        *(float4*)&xs[j] = xr[i];
        *(float4*)&wt[j] = wr[i];
    }
    __syncthreads();

    // compute phase 1
    for (int kq = 0; kq < 32; ++kq) {
        int k0 = kq * 4;
        float xv0 = xs[(k0 + 0) * BATCH + lane];
        float xv1 = xs[(k0 + 1) * BATCH + lane];
        float xv2 = xs[(k0 + 2) * BATCH + lane];
        float xv3 = xs[(k0 + 3) * BATCH + lane];
        #pragma unroll
        for (int nt = 0; nt < 16; ++nt) {
            float4 wv4 = *(const float4*)&wt[(wv * 16 + nt) * 128 + k0];
            acc[nt] += xv0 * wv4.x + xv1 * wv4.y + xv2 * wv4.z + xv3 * wv4.w;
        }
    }

    int nbase = n0 + wv * 16;
    #pragma unroll
    for (int nq = 0; nq < 4; ++nq) {
        float4 o;
        o.x = acc[nq * 4 + 0] + bias[nbase + nq * 4 + 0];
        o.y = acc[nq * 4 + 1] + bias[nbase + nq * 4 + 1];
        o.z = acc[nq * 4 + 2] + bias[nbase + nq * 4 + 2];
        o.w = acc[nq * 4 + 3] + bias[nbase + nq * 4 + 3];
        *(float4*)&y[(size_t)lane * FEAT + nbase + nq * 4] = o;
    }
}

// ---------------------------------------------------------------------------
extern "C" void kernel_launch(void* const* d_in, const int* in_sizes, int n_in,
                              void* d_out, int out_size, void* d_ws, size_t ws_size,
                              hipStream_t stream) {
    const float* images   = (const float*)d_in[0];
    const float* c1w      = (const float*)d_in[1];
    const float* c1b      = (const float*)d_in[2];
    const float* c2w      = (const float*)d_in[3];
    const float* c2b      = (const float*)d_in[4];
    const float* efw      = (const float*)d_in[5];
    const float* efb      = (const float*)d_in[6];
    const float* dfw      = (const float*)d_in[7];
    const float* dfb      = (const float*)d_in[8];
    const float* ct2w     = (const float*)d_in[9];
    const float* ct2b     = (const float*)d_in[10];
    const float* ct1w     = (const float*)d_in[11];
    const float* ct1b     = (const float*)d_in[12];
    const float* smw      = (const float*)d_in[13];
    const float* smb      = (const float*)d_in[14];
    const float* ll       = (const float*)d_in[15];

    float* out = (float*)d_out;
    float* ws  = (float*)d_ws;

    // ws layout (floats)
    float* big0 = ws;                                  // 64*64*784 = 3211264 (a2, later y)
    float* big1 = ws + 3211264;                        // 64*32*784 = 1605632 (a1, later ct2 out)
    float* part = ws + 3211264 + 1605632;              // 7*64*256 = 114688
    float* z    = part + KS * BATCH * LATENT;          // 16384
    float* whop = z + BATCH * LATENT;                  // 65536
    float* rho  = whop + LATENT * LATENT;              // 1
    float* xsa  = rho + 4;                             // 256*64 = 16384

    // encoder
    conv5_k<4,0><<<dim3(BATCH, 8), 256, 0, stream>>>(images, c1w, c1b, big1, 1, 32, 1);
    conv5_k<4,0><<<dim3(BATCH, 16), 256, 0, stream>>>(big1, c2w, c2b, big0, 32, 64, 1);
    enc_fc_part_k<<<dim3(64, KS), 256, 0, stream>>>(big0, efw, part);
    enc_fc_fin_k<<<BATCH, 256, 0, stream>>>(part, efb, z, xsa);

    // hopfield
    hop_rho_k<<<1, 256, 0, stream>>>(ll, rho);
    hop_w_k<<<LATENT, 256, 0, stream>>>(ll, rho, whop);
    cluster_k<<<BATCH, 1024, 0, stream>>>(z, whop, ll, out);           // cluster_probs
    class_k<<<BATCH, 256, 0, stream>>>(z, smw, smb, out + 640);        // class_probs

    // decoder
    dec_fc_k<<<FEAT / 64, 256, 0, stream>>>(xsa, dfw, dfb, big0);
    conv5_k<4,1><<<dim3(BATCH, 8), 256, 0, stream>>>(big0, ct2w, ct2b, big1, 64, 32, 1);
    conv5_k<1,1><<<dim3(BATCH, 1), 256, 0, stream>>>(big1, ct1w, ct1b, out + 1280, 32, 1, 0);
}